// Round 1
// baseline (599.898 us; speedup 1.0000x reference)
//
#include <hip/hip_runtime.h>
#include <hip/hip_bf16.h>
#include <stdint.h>
#include <float.h>

// VQ quantize: z[65536,256] f32, weight[1024,256] f32.
// ref (numpy fp32): d = fl32(fl32(A - 2*B) + C); idx = argmax(-d) (first-index ties).
// Outputs (float32, concat): quantized [65536*256], indices [65536].
//
// Pipeline:
//   1) to_bf16: z,w -> bf16 copies (scratch inside d_out; dead before gather)
//   2) rownorm_np: C=|w|^2 in exact numpy pairwise order
//   3) vq_screen: bf16 MFMA 16x16x32 GEMM (scores = C - 2*z.wT), per-row
//      (min1,min2,idx); rows with margin < TAU flagged. bf16 screen error
//      sigma~2e-5 on margins; TAU=2.5e-4 is ~12 sigma + sim-quantization.
//   4) vq_refine: flagged rows re-decided with bit-exact numpy-fp32 simulation
//      (pairwise A, sequential-k fma chain B) -- proven absmax=0 in round 3.
//      R4: one block per flagged row (was: 8-row batches serially walking 32
//      LDS code-chunks -> ~6 active blocks, 138us of sync/latency). Now each
//      thread owns 4 codes with 4 interleaved exact fma chains; codebook read
//      straight from L2. Same per-(row,code) arithmetic, bit-exact.
//   5) vq_gather.

constexpr int NROWS = 65536;
constexpr int D     = 256;
constexpr int CODES = 1024;

constexpr float TAU_SCREEN = 2.5e-4f;

typedef __attribute__((ext_vector_type(8))) short short8;   // 8 bf16 = 4 VGPR
typedef __attribute__((ext_vector_type(4))) float f32x4;

// ---------------- init ----------------
__global__ void init_ws(int* cnt) { if (threadIdx.x == 0) *cnt = 0; }

// ---------------- fp32 -> bf16 (RNE) ----------------
__device__ __forceinline__ unsigned short f2bf(float x) {
    union { __hip_bfloat16 h; unsigned short u; } c;
    c.h = __float2bfloat16(x);
    return c.u;
}

__global__ __launch_bounds__(256) void to_bf16(const float* __restrict__ src,
                                               unsigned short* __restrict__ dst,
                                               int n8) {
    const int i = blockIdx.x * 256 + threadIdx.x;
    if (i >= n8) return;
    const float4* s = (const float4*)src + (size_t)i * 2;
    float4 a = s[0], b = s[1];
    union { unsigned short u[8]; uint4 v; } p;
    p.u[0] = f2bf(a.x); p.u[1] = f2bf(a.y); p.u[2] = f2bf(a.z); p.u[3] = f2bf(a.w);
    p.u[4] = f2bf(b.x); p.u[5] = f2bf(b.y); p.u[6] = f2bf(b.z); p.u[7] = f2bf(b.w);
    *(uint4*)(dst + (size_t)i * 8) = p.v;
}

// ---------------- exact numpy pairwise |row|^2 ----------------
__device__ __forceinline__ float np_pairwise_sq256(const float* a) {
    float res[2];
    #pragma unroll
    for (int b = 0; b < 2; ++b) {
        float r[8];
        #pragma unroll
        for (int j = 0; j < 8; ++j) r[j] = 0.f;
        #pragma unroll
        for (int m = 0; m < 16; ++m) {
            const int base = b * 128 + m * 8;
            #pragma unroll
            for (int j = 0; j < 8; ++j)
                r[j] = __fadd_rn(r[j], __fmul_rn(a[base + j], a[base + j]));
        }
        res[b] = __fadd_rn(__fadd_rn(__fadd_rn(r[0], r[1]), __fadd_rn(r[2], r[3])),
                           __fadd_rn(__fadd_rn(r[4], r[5]), __fadd_rn(r[6], r[7])));
    }
    return __fadd_rn(res[0], res[1]);
}

__global__ __launch_bounds__(256) void rownorm_np(const float* __restrict__ x,
                                                  float* __restrict__ out, int nrows) {
    const int row = blockIdx.x * 256 + threadIdx.x;
    if (row >= nrows) return;
    float a[256];
    const float4* p = (const float4*)(x + (size_t)row * D);
    #pragma unroll
    for (int k4 = 0; k4 < 64; ++k4) {
        float4 v = p[k4];
        a[k4 * 4 + 0] = v.x; a[k4 * 4 + 1] = v.y;
        a[k4 * 4 + 2] = v.z; a[k4 * 4 + 3] = v.w;
    }
    out[row] = np_pairwise_sq256(a);
}

// ---------------- bf16 MFMA screen ----------------
// block = 128 rows x all 1024 codes (8 n-blocks looped), 4 waves (2x2),
// each wave 64x64 via 4x4 tiles of mfma_f32_16x16x32_bf16.
// LDS tiles [row][64k] bf16, 16B chunks XOR-swizzled by (row&7) -> conflict-free
// b128 fragment reads. Frag layouts (m89/m91-verified):
//   A: lane l holds A[m=l&15][k=(l>>4)*8+j]; B (from W row-major [code][k]) same;
//   D: row=(l>>4)*4+reg, col=l&15.
__global__ __launch_bounds__(256, 2) void vq_screen(const unsigned short* __restrict__ zbf,
                                                    const unsigned short* __restrict__ wbf,
                                                    const float* __restrict__ Cn,
                                                    int* __restrict__ idx_out,
                                                    int* __restrict__ flagged,
                                                    int* __restrict__ cnt) {
    __shared__ unsigned short zT[128 * 64];
    __shared__ unsigned short wT[128 * 64];
    __shared__ float Cs[1024];
    __shared__ float rm1s[2][128];
    __shared__ float rm2s[2][128];
    __shared__ int   ris[2][128];

    const int t    = threadIdx.x;
    const int wv   = t >> 6;          // wave 0..3
    const int l    = t & 63;
    const int wm   = wv >> 1;         // row half
    const int wn   = wv & 1;          // col half
    const int m    = l & 15;
    const int quad = l >> 4;
    const int row0 = blockIdx.x * 128;

    for (int i = t; i < 1024; i += 256) Cs[i] = Cn[i];

    float m1[4][4], m2[4][4];
    int   bi[4][4];
    #pragma unroll
    for (int mi = 0; mi < 4; ++mi)
        #pragma unroll
        for (int r = 0; r < 4; ++r) { m1[mi][r] = FLT_MAX; m2[mi][r] = FLT_MAX; bi[mi][r] = 0; }

    const int sr  = t & 127;          // staging row
    const int ssw = sr & 7;           // staging swizzle

    for (int nb = 0; nb < 8; ++nb) {
        f32x4 acc[4][4];
        #pragma unroll
        for (int mi = 0; mi < 4; ++mi)
            #pragma unroll
            for (int ni = 0; ni < 4; ++ni) acc[mi][ni] = (f32x4){0.f, 0.f, 0.f, 0.f};

        for (int ks = 0; ks < 4; ++ks) {
            __syncthreads();
            {
                const unsigned short* src = (t < 128)
                    ? zbf + ((size_t)(row0 + sr) * D + ks * 64)
                    : wbf + ((size_t)(nb * 128 + sr) * D + ks * 64);
                unsigned short* dst = (t < 128) ? &zT[sr * 64] : &wT[sr * 64];
                #pragma unroll
                for (int c = 0; c < 8; ++c) {
                    uint4 v = *(const uint4*)(src + c * 8);
                    *(uint4*)(dst + ((c ^ ssw) * 8)) = v;
                }
            }
            __syncthreads();
            #pragma unroll
            for (int kk = 0; kk < 2; ++kk) {
                short8 a[4], b[4];
                const int ch = kk * 4 + quad;
                #pragma unroll
                for (int mi = 0; mi < 4; ++mi) {
                    const int rr = wm * 64 + mi * 16 + m;
                    a[mi] = *(const short8*)&zT[rr * 64 + ((ch ^ (m & 7)) * 8)];
                }
                #pragma unroll
                for (int ni = 0; ni < 4; ++ni) {
                    const int rr = wn * 64 + ni * 16 + m;
                    b[ni] = *(const short8*)&wT[rr * 64 + ((ch ^ (m & 7)) * 8)];
                }
                #pragma unroll
                for (int mi = 0; mi < 4; ++mi)
                    #pragma unroll
                    for (int ni = 0; ni < 4; ++ni)
                        acc[mi][ni] = __builtin_amdgcn_mfma_f32_16x16x32_bf16(
                            a[mi], b[ni], acc[mi][ni], 0, 0, 0);
            }
        }
        // epilogue for this n-block: v = C - 2B ; update per-lane (min1,min2,idx)
        #pragma unroll
        for (int ni = 0; ni < 4; ++ni) {
            const int code = nb * 128 + wn * 64 + ni * 16 + m;
            const float c  = Cs[code];
            #pragma unroll
            for (int mi = 0; mi < 4; ++mi)
                #pragma unroll
                for (int r = 0; r < 4; ++r) {
                    const float v = fmaf(-2.0f, acc[mi][ni][r], c);
                    if (v < m1[mi][r]) { m2[mi][r] = m1[mi][r]; m1[mi][r] = v; bi[mi][r] = code; }
                    else if (v < m2[mi][r]) m2[mi][r] = v;
                }
        }
    }

    // reduce across the 16 col-lanes (xor 1,2,4,8 varies l&15 only).
    // screen ties need no idx tie-break: equal mins -> margin 0 -> flagged -> exact.
    #pragma unroll
    for (int mi = 0; mi < 4; ++mi)
        #pragma unroll
        for (int r = 0; r < 4; ++r) {
            float a1 = m1[mi][r], a2 = m2[mi][r];
            int   ai = bi[mi][r];
            #pragma unroll
            for (int off = 1; off <= 8; off <<= 1) {
                float o1 = __shfl_xor(a1, off, 64);
                float o2 = __shfl_xor(a2, off, 64);
                int   oi = __shfl_xor(ai, off, 64);
                float n2 = fminf(a2, o2);
                if (o1 < a1) { n2 = fminf(n2, a1); a1 = o1; ai = oi; }
                else n2 = fminf(n2, o1);
                a2 = n2;
            }
            m1[mi][r] = a1; m2[mi][r] = a2; bi[mi][r] = ai;
        }

    if (m == 0) {
        #pragma unroll
        for (int mi = 0; mi < 4; ++mi)
            #pragma unroll
            for (int r = 0; r < 4; ++r) {
                const int rl = wm * 64 + mi * 16 + quad * 4 + r;
                rm1s[wn][rl] = m1[mi][r];
                rm2s[wn][rl] = m2[mi][r];
                ris[wn][rl]  = bi[mi][r];
            }
    }
    __syncthreads();
    if (t < 128) {
        float a1 = rm1s[0][t], a2 = rm2s[0][t];
        int   ai = ris[0][t];
        const float o1 = rm1s[1][t], o2 = rm2s[1][t];
        const int   oi = ris[1][t];
        float n2 = fminf(a2, o2);
        if (o1 < a1) { n2 = fminf(n2, a1); a1 = o1; ai = oi; }
        else n2 = fminf(n2, o1);
        a2 = n2;
        const int row = row0 + t;
        idx_out[row] = ai;
        if (a2 - a1 < TAU_SCREEN) {
            int p = atomicAdd(cnt, 1);
            flagged[p] = row;
        }
    }
}

// ---------------- exact numpy-sim refine (proven, round 3; R4 restructure) ----------------
// One block per flagged row (grid-stride). 256 threads; thread t owns codes
// {t, t+256, t+512, t+768} as 4 interleaved, independent sequential-fma chains
// (per-chain order identical to the proven bit-exact chain). z-row staged in
// LDS once (broadcast reads); codebook (1 MB, L2-resident) read directly from
// global. LDS tree argmin with explicit (d, code) tie-break.
__global__ __launch_bounds__(256) void vq_refine(const float* __restrict__ z,
                                                 const float* __restrict__ w,
                                                 const float* __restrict__ Cn,
                                                 const int* __restrict__ flagged,
                                                 const int* __restrict__ cnt,
                                                 int* __restrict__ idx_out) {
    __shared__ float zrow[256];
    __shared__ float bestd[256];
    __shared__ int   besti[256];

    const int t = threadIdx.x;
    const int n = *cnt;

    for (int f = blockIdx.x; f < n; f += gridDim.x) {
        __syncthreads();                       // zrow/bestd reuse across iterations
        const int row = flagged[f];
        if (t < 64)
            ((float4*)zrow)[t] = ((const float4*)(z + (size_t)row * D))[t];
        __syncthreads();

        // exact numpy pairwise A, computed redundantly by all threads
        // (LDS broadcast reads; bit-identical across threads)
        const float A = np_pairwise_sq256(zrow);

        const float4* wp0 = (const float4*)(w + (size_t)(t)       * D);
        const float4* wp1 = (const float4*)(w + (size_t)(t + 256) * D);
        const float4* wp2 = (const float4*)(w + (size_t)(t + 512) * D);
        const float4* wp3 = (const float4*)(w + (size_t)(t + 768) * D);
        float B0 = 0.f, B1 = 0.f, B2 = 0.f, B3 = 0.f;
        #pragma unroll 8
        for (int k4 = 0; k4 < 64; ++k4) {
            const float4 zv = *(const float4*)&zrow[k4 * 4];
            const float4 w0 = wp0[k4];
            const float4 w1 = wp1[k4];
            const float4 w2 = wp2[k4];
            const float4 w3 = wp3[k4];
            B0 = fmaf(zv.x, w0.x, B0); B0 = fmaf(zv.y, w0.y, B0);
            B0 = fmaf(zv.z, w0.z, B0); B0 = fmaf(zv.w, w0.w, B0);
            B1 = fmaf(zv.x, w1.x, B1); B1 = fmaf(zv.y, w1.y, B1);
            B1 = fmaf(zv.z, w1.z, B1); B1 = fmaf(zv.w, w1.w, B1);
            B2 = fmaf(zv.x, w2.x, B2); B2 = fmaf(zv.y, w2.y, B2);
            B2 = fmaf(zv.z, w2.z, B2); B2 = fmaf(zv.w, w2.w, B2);
            B3 = fmaf(zv.x, w3.x, B3); B3 = fmaf(zv.y, w3.y, B3);
            B3 = fmaf(zv.z, w3.z, B3); B3 = fmaf(zv.w, w3.w, B3);
        }
        const float d0 = __fadd_rn(__fsub_rn(A, __fmul_rn(2.0f, B0)), Cn[t]);
        const float d1 = __fadd_rn(__fsub_rn(A, __fmul_rn(2.0f, B1)), Cn[t + 256]);
        const float d2 = __fadd_rn(__fsub_rn(A, __fmul_rn(2.0f, B2)), Cn[t + 512]);
        const float d3 = __fadd_rn(__fsub_rn(A, __fmul_rn(2.0f, B3)), Cn[t + 768]);

        // per-thread best; codes ascending, strict < keeps smallest code on tie
        float bd = d0; int bi = t;
        if (d1 < bd) { bd = d1; bi = t + 256; }
        if (d2 < bd) { bd = d2; bi = t + 512; }
        if (d3 < bd) { bd = d3; bi = t + 768; }

        bestd[t] = bd; besti[t] = bi;
        __syncthreads();
        for (int off = 128; off >= 1; off >>= 1) {
            if (t < off) {
                const float od = bestd[t + off];
                const int   oi = besti[t + off];
                if (od < bestd[t] || (od == bestd[t] && oi < besti[t])) {
                    bestd[t] = od; besti[t] = oi;
                }
            }
            __syncthreads();
        }
        if (t == 0) idx_out[row] = besti[0];
    }
}

// ---------------- gather ----------------
__global__ __launch_bounds__(256) void vq_gather(const float* __restrict__ w,
                                                 const int* __restrict__ idx,
                                                 float* __restrict__ outq,
                                                 float* __restrict__ outi) {
    const int t    = threadIdx.x;
    const int lane = t & 63;
    const int sub  = t >> 6;
    const int row0 = blockIdx.x * 128;
    #pragma unroll 4
    for (int it = 0; it < 32; ++it) {
        const int row = row0 + it * 4 + sub;
        const int j   = idx[row];
        ((float4*)outq)[(size_t)row * 64 + lane] = ((const float4*)w)[(size_t)j * 64 + lane];
        if (lane == 0) outi[row] = (float)j;
    }
}

extern "C" void kernel_launch(void* const* d_in, const int* in_sizes, int n_in,
                              void* d_out, int out_size, void* d_ws, size_t ws_size,
                              hipStream_t stream) {
    const float* z = (const float*)d_in[0];
    const float* w = (const float*)d_in[1];
    float* outq = (float*)d_out;
    float* outi = outq + (size_t)NROWS * D;

    // scratch inside d_out (dead before vq_gather overwrites it):
    //   zbf [0, 32MB) | wbf [32MB, +512KB) | Cn [+4KB)
    unsigned short* zbf = (unsigned short*)d_out;
    unsigned short* wbf = (unsigned short*)((char*)d_out + 33554432);
    float*          Cn  = (float*)((char*)d_out + 34078720);

    char* ws      = (char*)d_ws;
    int*  idx     = (int*)ws;
    int*  flagged = (int*)(ws + 262144);
    int*  cnt     = (int*)(ws + 524288);

    init_ws<<<1, 64, 0, stream>>>(cnt);
    to_bf16<<<NROWS * D / 8 / 256, 256, 0, stream>>>(z, zbf, NROWS * D / 8);
    to_bf16<<<CODES * D / 8 / 256, 256, 0, stream>>>(w, wbf, CODES * D / 8);
    rownorm_np<<<(CODES + 255) / 256, 256, 0, stream>>>(w, Cn, CODES);
    vq_screen<<<NROWS / 128, 256, 0, stream>>>(zbf, wbf, Cn, idx, flagged, cnt);
    vq_refine<<<512, 256, 0, stream>>>(z, w, Cn, flagged, cnt, idx);
    vq_gather<<<NROWS / 128, 256, 0, stream>>>(w, idx, outq, outi);
}

// Round 2
// 361.482 us; speedup vs baseline: 1.6596x; 1.6596x over previous
//
#include <hip/hip_runtime.h>
#include <hip/hip_bf16.h>
#include <stdint.h>
#include <float.h>

// VQ quantize: z[65536,256] f32, weight[1024,256] f32.
// ref (numpy fp32): d = fl32(fl32(A - 2*B) + C); idx = argmax(-d) (first-index ties).
// Outputs (float32, concat): quantized [65536*256], indices [65536].
//
// Pipeline:
//   1) to_bf16: z,w -> bf16 copies (scratch inside d_out; dead before gather)
//   2) rownorm_np: C=|w|^2 in exact numpy pairwise order
//   3) vq_screen: bf16 MFMA 16x16x32 GEMM (scores = C - 2*z.wT), per-row
//      (min1,min2,idx); rows with margin < TAU flagged (n ~ 4700 rows, 7%).
//   4) vq_refine: flagged rows re-decided with bit-exact numpy-fp32 simulation.
//      R5: tile = 24 rows/block (amortize codebook; R4's 1-row/block re-read
//      1MB per row = 4.7GB L2 -> 390us). Codebook streamed in 64-code chunks,
//      double-buffered via global_load_lds; wave owns 6 rows (6 fma chains,
//      w amortized 6x -> LDS BW ~0.7B/fma < 1B/cyc/lane budget); z reads are
//      wave-uniform LDS broadcasts. Exact chain per (row,code) unchanged.
//   5) vq_gather.

constexpr int NROWS = 65536;
constexpr int D     = 256;
constexpr int CODES = 1024;

constexpr float TAU_SCREEN = 2.5e-4f;

// refine tiling
constexpr int RT   = 24;              // flagged rows per block
constexpr int WCH  = 64;              // codes per chunk
constexpr int NCH  = CODES / WCH;     // 16 chunks
constexpr int WSTR = 260;             // padded f32 stride for w rows (16B-aligned, bank-spread)

typedef __attribute__((ext_vector_type(8))) short short8;   // 8 bf16 = 4 VGPR
typedef __attribute__((ext_vector_type(4))) float f32x4;

// global -> LDS async 16B copy: per-lane global src, wave-uniform LDS base,
// HW writes lane l -> base + l*16 (m97/m104 semantics).
__device__ __forceinline__ void gl2lds16(const float* g, float* l) {
    __builtin_amdgcn_global_load_lds(
        (const __attribute__((address_space(1))) void*)g,
        (__attribute__((address_space(3))) void*)l, 16, 0, 0);
}

// ---------------- init ----------------
__global__ void init_ws(int* cnt) { if (threadIdx.x == 0) *cnt = 0; }

// ---------------- fp32 -> bf16 (RNE) ----------------
__device__ __forceinline__ unsigned short f2bf(float x) {
    union { __hip_bfloat16 h; unsigned short u; } c;
    c.h = __float2bfloat16(x);
    return c.u;
}

__global__ __launch_bounds__(256) void to_bf16(const float* __restrict__ src,
                                               unsigned short* __restrict__ dst,
                                               int n8) {
    const int i = blockIdx.x * 256 + threadIdx.x;
    if (i >= n8) return;
    const float4* s = (const float4*)src + (size_t)i * 2;
    float4 a = s[0], b = s[1];
    union { unsigned short u[8]; uint4 v; } p;
    p.u[0] = f2bf(a.x); p.u[1] = f2bf(a.y); p.u[2] = f2bf(a.z); p.u[3] = f2bf(a.w);
    p.u[4] = f2bf(b.x); p.u[5] = f2bf(b.y); p.u[6] = f2bf(b.z); p.u[7] = f2bf(b.w);
    *(uint4*)(dst + (size_t)i * 8) = p.v;
}

// ---------------- exact numpy pairwise |row|^2 ----------------
__device__ __forceinline__ float np_pairwise_sq256(const float* a) {
    float res[2];
    #pragma unroll
    for (int b = 0; b < 2; ++b) {
        float r[8];
        #pragma unroll
        for (int j = 0; j < 8; ++j) r[j] = 0.f;
        #pragma unroll
        for (int m = 0; m < 16; ++m) {
            const int base = b * 128 + m * 8;
            #pragma unroll
            for (int j = 0; j < 8; ++j)
                r[j] = __fadd_rn(r[j], __fmul_rn(a[base + j], a[base + j]));
        }
        res[b] = __fadd_rn(__fadd_rn(__fadd_rn(r[0], r[1]), __fadd_rn(r[2], r[3])),
                           __fadd_rn(__fadd_rn(r[4], r[5]), __fadd_rn(r[6], r[7])));
    }
    return __fadd_rn(res[0], res[1]);
}

__global__ __launch_bounds__(256) void rownorm_np(const float* __restrict__ x,
                                                  float* __restrict__ out, int nrows) {
    const int row = blockIdx.x * 256 + threadIdx.x;
    if (row >= nrows) return;
    float a[256];
    const float4* p = (const float4*)(x + (size_t)row * D);
    #pragma unroll
    for (int k4 = 0; k4 < 64; ++k4) {
        float4 v = p[k4];
        a[k4 * 4 + 0] = v.x; a[k4 * 4 + 1] = v.y;
        a[k4 * 4 + 2] = v.z; a[k4 * 4 + 3] = v.w;
    }
    out[row] = np_pairwise_sq256(a);
}

// ---------------- bf16 MFMA screen (unchanged, proven) ----------------
__global__ __launch_bounds__(256, 2) void vq_screen(const unsigned short* __restrict__ zbf,
                                                    const unsigned short* __restrict__ wbf,
                                                    const float* __restrict__ Cn,
                                                    int* __restrict__ idx_out,
                                                    int* __restrict__ flagged,
                                                    int* __restrict__ cnt) {
    __shared__ unsigned short zT[128 * 64];
    __shared__ unsigned short wT[128 * 64];
    __shared__ float Cs[1024];
    __shared__ float rm1s[2][128];
    __shared__ float rm2s[2][128];
    __shared__ int   ris[2][128];

    const int t    = threadIdx.x;
    const int wv   = t >> 6;          // wave 0..3
    const int l    = t & 63;
    const int wm   = wv >> 1;         // row half
    const int wn   = wv & 1;          // col half
    const int m    = l & 15;
    const int quad = l >> 4;
    const int row0 = blockIdx.x * 128;

    for (int i = t; i < 1024; i += 256) Cs[i] = Cn[i];

    float m1[4][4], m2[4][4];
    int   bi[4][4];
    #pragma unroll
    for (int mi = 0; mi < 4; ++mi)
        #pragma unroll
        for (int r = 0; r < 4; ++r) { m1[mi][r] = FLT_MAX; m2[mi][r] = FLT_MAX; bi[mi][r] = 0; }

    const int sr  = t & 127;          // staging row
    const int ssw = sr & 7;           // staging swizzle

    for (int nb = 0; nb < 8; ++nb) {
        f32x4 acc[4][4];
        #pragma unroll
        for (int mi = 0; mi < 4; ++mi)
            #pragma unroll
            for (int ni = 0; ni < 4; ++ni) acc[mi][ni] = (f32x4){0.f, 0.f, 0.f, 0.f};

        for (int ks = 0; ks < 4; ++ks) {
            __syncthreads();
            {
                const unsigned short* src = (t < 128)
                    ? zbf + ((size_t)(row0 + sr) * D + ks * 64)
                    : wbf + ((size_t)(nb * 128 + sr) * D + ks * 64);
                unsigned short* dst = (t < 128) ? &zT[sr * 64] : &wT[sr * 64];
                #pragma unroll
                for (int c = 0; c < 8; ++c) {
                    uint4 v = *(const uint4*)(src + c * 8);
                    *(uint4*)(dst + ((c ^ ssw) * 8)) = v;
                }
            }
            __syncthreads();
            #pragma unroll
            for (int kk = 0; kk < 2; ++kk) {
                short8 a[4], b[4];
                const int ch = kk * 4 + quad;
                #pragma unroll
                for (int mi = 0; mi < 4; ++mi) {
                    const int rr = wm * 64 + mi * 16 + m;
                    a[mi] = *(const short8*)&zT[rr * 64 + ((ch ^ (m & 7)) * 8)];
                }
                #pragma unroll
                for (int ni = 0; ni < 4; ++ni) {
                    const int rr = wn * 64 + ni * 16 + m;
                    b[ni] = *(const short8*)&wT[rr * 64 + ((ch ^ (m & 7)) * 8)];
                }
                #pragma unroll
                for (int mi = 0; mi < 4; ++mi)
                    #pragma unroll
                    for (int ni = 0; ni < 4; ++ni)
                        acc[mi][ni] = __builtin_amdgcn_mfma_f32_16x16x32_bf16(
                            a[mi], b[ni], acc[mi][ni], 0, 0, 0);
            }
        }
        #pragma unroll
        for (int ni = 0; ni < 4; ++ni) {
            const int code = nb * 128 + wn * 64 + ni * 16 + m;
            const float c  = Cs[code];
            #pragma unroll
            for (int mi = 0; mi < 4; ++mi)
                #pragma unroll
                for (int r = 0; r < 4; ++r) {
                    const float v = fmaf(-2.0f, acc[mi][ni][r], c);
                    if (v < m1[mi][r]) { m2[mi][r] = m1[mi][r]; m1[mi][r] = v; bi[mi][r] = code; }
                    else if (v < m2[mi][r]) m2[mi][r] = v;
                }
        }
    }

    #pragma unroll
    for (int mi = 0; mi < 4; ++mi)
        #pragma unroll
        for (int r = 0; r < 4; ++r) {
            float a1 = m1[mi][r], a2 = m2[mi][r];
            int   ai = bi[mi][r];
            #pragma unroll
            for (int off = 1; off <= 8; off <<= 1) {
                float o1 = __shfl_xor(a1, off, 64);
                float o2 = __shfl_xor(a2, off, 64);
                int   oi = __shfl_xor(ai, off, 64);
                float n2 = fminf(a2, o2);
                if (o1 < a1) { n2 = fminf(n2, a1); a1 = o1; ai = oi; }
                else n2 = fminf(n2, o1);
                a2 = n2;
            }
            m1[mi][r] = a1; m2[mi][r] = a2; bi[mi][r] = ai;
        }

    if (m == 0) {
        #pragma unroll
        for (int mi = 0; mi < 4; ++mi)
            #pragma unroll
            for (int r = 0; r < 4; ++r) {
                const int rl = wm * 64 + mi * 16 + quad * 4 + r;
                rm1s[wn][rl] = m1[mi][r];
                rm2s[wn][rl] = m2[mi][r];
                ris[wn][rl]  = bi[mi][r];
            }
    }
    __syncthreads();
    if (t < 128) {
        float a1 = rm1s[0][t], a2 = rm2s[0][t];
        int   ai = ris[0][t];
        const float o1 = rm1s[1][t], o2 = rm2s[1][t];
        const int   oi = ris[1][t];
        float n2 = fminf(a2, o2);
        if (o1 < a1) { n2 = fminf(n2, a1); a1 = o1; ai = oi; }
        else n2 = fminf(n2, o1);
        a2 = n2;
        const int row = row0 + t;
        idx_out[row] = ai;
        if (a2 - a1 < TAU_SCREEN) {
            int p = atomicAdd(cnt, 1);
            flagged[p] = row;
        }
    }
}

// ---------------- exact numpy-sim refine (R5: 24-row tiles, dbuf codebook) ----------------
// Block = 24 flagged rows x all 1024 codes. 4 waves; wave v owns rows 6v..6v+5.
// Per 64-code chunk: lane l owns code c*64+l -> 6 independent exact fma chains
// (z broadcast from LDS, w from padded LDS rows). Codebook double-buffered via
// global_load_lds (wave-uniform LDS row base + lane*16B; pad preserved).
// Argmin: lexicographic (d, code) shuffle-reduce per row (rows wave-exclusive).
__global__ __launch_bounds__(256) void vq_refine(const float* __restrict__ z,
                                                 const float* __restrict__ w,
                                                 const float* __restrict__ Cn,
                                                 const int* __restrict__ flagged,
                                                 const int* __restrict__ cnt,
                                                 int* __restrict__ idx_out) {
    __shared__ float zl[RT * 256];          // 24 KB, unpadded (broadcast reads)
    __shared__ float wl[2 * WCH * WSTR];    // 130 KB, double-buffered, padded rows
    __shared__ float sA[RT];
    __shared__ float pp[RT * 16];
    __shared__ int   rid[RT];

    const int t  = threadIdx.x;
    const int l  = t & 63;
    const int wv = t >> 6;
    const int r0 = wv * 6;                  // this wave's first row
    const int n  = *cnt;

    for (int tile = blockIdx.x; tile * RT < n; tile += gridDim.x) {
        __syncthreads();                    // LDS reuse guard across tiles
        if (t < RT) {
            const int fi = tile * RT + t;
            rid[t] = (fi < n) ? flagged[fi] : -1;
        }
        __syncthreads();

        // stage z rows (24) + w chunk 0 (async, direct-to-LDS)
        for (int i = wv; i < RT; i += 4) {
            const int rr = rid[i] < 0 ? 0 : rid[i];
            gl2lds16(z + (size_t)rr * D + (l << 2), &zl[i * 256]);
        }
        for (int i = wv; i < WCH; i += 4)
            gl2lds16(w + (size_t)i * D + (l << 2), &wl[i * WSTR]);
        asm volatile("s_waitcnt vmcnt(0)" ::: "memory");
        __syncthreads();

        // exact A: partials in the identical numpy pairwise order
        if (t < RT * 8) {
            const int r = t >> 3, j = t & 7;
            const float* a = &zl[r * 256];
            #pragma unroll
            for (int b = 0; b < 2; ++b) {
                float acc = 0.f;
                #pragma unroll
                for (int m = 0; m < 16; ++m) {
                    const float v = a[b * 128 + m * 8 + j];
                    acc = __fadd_rn(acc, __fmul_rn(v, v));
                }
                pp[r * 16 + b * 8 + j] = acc;
            }
        }
        __syncthreads();
        if (t < RT) {
            const float* q = &pp[t * 16];
            const float res0 = __fadd_rn(__fadd_rn(__fadd_rn(q[0], q[1]), __fadd_rn(q[2], q[3])),
                                         __fadd_rn(__fadd_rn(q[4], q[5]), __fadd_rn(q[6], q[7])));
            const float res1 = __fadd_rn(__fadd_rn(__fadd_rn(q[8], q[9]), __fadd_rn(q[10], q[11])),
                                         __fadd_rn(__fadd_rn(q[12], q[13]), __fadd_rn(q[14], q[15])));
            sA[t] = __fadd_rn(res0, res1);
        }
        __syncthreads();

        float Ar[6];
        float bd[6];
        int   bic[6];
        #pragma unroll
        for (int i = 0; i < 6; ++i) {
            Ar[i]  = sA[r0 + i];
            bd[i]  = FLT_MAX;
            bic[i] = 0x7fffffff;
        }

        for (int c = 0; c < NCH; ++c) {
            const int cur = c & 1;
            if (c + 1 < NCH) {                     // prefetch next chunk -> other buffer
                const int c0n = (c + 1) * WCH;
                float* dstb = &wl[((c + 1) & 1) * WCH * WSTR];
                for (int i = wv; i < WCH; i += 4)
                    gl2lds16(w + (size_t)(c0n + i) * D + (l << 2), dstb + i * WSTR);
            }
            // 6 exact chains: code = c*64 + l, rows r0..r0+5
            float B[6] = {0.f, 0.f, 0.f, 0.f, 0.f, 0.f};
            const float* wrow = &wl[cur * WCH * WSTR + l * WSTR];
            #pragma unroll 4
            for (int k4 = 0; k4 < 64; ++k4) {
                const float4 wv4 = *(const float4*)&wrow[k4 * 4];
                #pragma unroll
                for (int i = 0; i < 6; ++i) {
                    const float4 zv = *(const float4*)&zl[(r0 + i) * 256 + k4 * 4];
                    B[i] = fmaf(zv.x, wv4.x, B[i]);
                    B[i] = fmaf(zv.y, wv4.y, B[i]);
                    B[i] = fmaf(zv.z, wv4.z, B[i]);
                    B[i] = fmaf(zv.w, wv4.w, B[i]);
                }
            }
            const int   code = c * WCH + l;
            const float Cc   = Cn[code];
            #pragma unroll
            for (int i = 0; i < 6; ++i) {
                const float d = __fadd_rn(__fsub_rn(Ar[i], __fmul_rn(2.0f, B[i])), Cc);
                if (d < bd[i] || (d == bd[i] && code < bic[i])) { bd[i] = d; bic[i] = code; }
            }
            asm volatile("s_waitcnt vmcnt(0)" ::: "memory");
            __syncthreads();                       // next chunk staged + all done reading cur
        }

        // per-row argmin across the 64 lanes, lexicographic (d, code)
        #pragma unroll
        for (int i = 0; i < 6; ++i) {
            float d  = bd[i];
            int   ci = bic[i];
            #pragma unroll
            for (int off = 1; off < 64; off <<= 1) {
                const float od = __shfl_xor(d, off, 64);
                const int   oc = __shfl_xor(ci, off, 64);
                if (od < d || (od == d && oc < ci)) { d = od; ci = oc; }
            }
            if (l == 0) {
                const int row = rid[r0 + i];
                if (row >= 0) idx_out[row] = ci;
            }
        }
    }
}

// ---------------- gather ----------------
__global__ __launch_bounds__(256) void vq_gather(const float* __restrict__ w,
                                                 const int* __restrict__ idx,
                                                 float* __restrict__ outq,
                                                 float* __restrict__ outi) {
    const int t    = threadIdx.x;
    const int lane = t & 63;
    const int sub  = t >> 6;
    const int row0 = blockIdx.x * 128;
    #pragma unroll 4
    for (int it = 0; it < 32; ++it) {
        const int row = row0 + it * 4 + sub;
        const int j   = idx[row];
        ((float4*)outq)[(size_t)row * 64 + lane] = ((const float4*)w)[(size_t)j * 64 + lane];
        if (lane == 0) outi[row] = (float)j;
    }
}

extern "C" void kernel_launch(void* const* d_in, const int* in_sizes, int n_in,
                              void* d_out, int out_size, void* d_ws, size_t ws_size,
                              hipStream_t stream) {
    const float* z = (const float*)d_in[0];
    const float* w = (const float*)d_in[1];
    float* outq = (float*)d_out;
    float* outi = outq + (size_t)NROWS * D;

    // scratch inside d_out (dead before vq_gather overwrites it):
    //   zbf [0, 32MB) | wbf [32MB, +512KB) | Cn [+4KB)
    unsigned short* zbf = (unsigned short*)d_out;
    unsigned short* wbf = (unsigned short*)((char*)d_out + 33554432);
    float*          Cn  = (float*)((char*)d_out + 34078720);

    char* ws      = (char*)d_ws;
    int*  idx     = (int*)ws;
    int*  flagged = (int*)(ws + 262144);
    int*  cnt     = (int*)(ws + 524288);

    init_ws<<<1, 64, 0, stream>>>(cnt);
    to_bf16<<<NROWS * D / 8 / 256, 256, 0, stream>>>(z, zbf, NROWS * D / 8);
    to_bf16<<<CODES * D / 8 / 256, 256, 0, stream>>>(w, wbf, CODES * D / 8);
    rownorm_np<<<(CODES + 255) / 256, 256, 0, stream>>>(w, Cn, CODES);
    vq_screen<<<NROWS / 128, 256, 0, stream>>>(zbf, wbf, Cn, idx, flagged, cnt);
    vq_refine<<<256, 256, 0, stream>>>(z, w, Cn, flagged, cnt, idx);
    vq_gather<<<NROWS / 128, 256, 0, stream>>>(w, idx, outq, outi);
}

// Round 3
// 329.860 us; speedup vs baseline: 1.8186x; 1.0959x over previous
//
#include <hip/hip_runtime.h>
#include <hip/hip_bf16.h>
#include <stdint.h>
#include <float.h>

// VQ quantize: z[65536,256] f32, weight[1024,256] f32.
// ref (numpy fp32): d = fl32(fl32(A - 2*B) + C); idx = argmax(-d) (first-index ties).
// Outputs (float32, concat): quantized [65536*256], indices [65536].
//
// Pipeline:
//   1) to_bf16: z,w -> bf16 copies (scratch inside d_out; dead before gather)
//   2) rownorm_np: C=|w|^2 in exact numpy pairwise order
//   3) vq_screen: bf16 MFMA 16x16x32 GEMM (scores = C - 2*z.wT), per-row
//      (min1,min2,idx); rows with margin < TAU flagged (n ~ 4700, 7%).
//      R6: also stores per-row min1 (m1g) for the candidate test.
//   4) vq_cand: MFMA-recompute scores for flagged rows (gathered tiles of
//      128 rows x 128 codes); emit (row,code) pairs with score < m1g+TAU.
//      Same trust as flagging itself: per-pair screen error < TAU => the
//      exact argmin is always in the candidate set (~2.3 codes/row).
//   5) vq_exact: one lane per pair; bit-exact numpy-fp32 chain (pairwise A,
//      sequential-k fma B -- proven absmax=0); atomicMin of packed
//      (ordered-d, code) per row => smallest d, then smallest code.
//   6) vq_unpack: idx[row] = low32(packed[row]) for flagged rows.
//   7) vq_gather.
//   R2's full-exact refine (all 1024 codes/row) was LDS-pipe-bound at 142us
//   (7 ds_read_b128 x 12cyc per 24 fma); candidates cut exact work 450x.

constexpr int NROWS = 65536;
constexpr int D     = 256;
constexpr int CODES = 1024;

constexpr float TAU_SCREEN = 2.5e-4f;
constexpr int   MAXPAIRS   = 7000000;   // pairs region cap (31MB/4B); expect ~11K

typedef __attribute__((ext_vector_type(8))) short short8;   // 8 bf16 = 4 VGPR
typedef __attribute__((ext_vector_type(4))) float f32x4;

// ---------------- init ----------------
__global__ __launch_bounds__(256) void init_ws(int* cnt, int* pcnt,
                                               unsigned long long* packed) {
    if (blockIdx.x == 0 && threadIdx.x == 0) { *cnt = 0; *pcnt = 0; }
    const int i = blockIdx.x * 256 + threadIdx.x;   // grid 256x256 = 65536
    if (i < NROWS) packed[i] = ~0ull;
}

// ---------------- fp32 -> bf16 (RNE) ----------------
__device__ __forceinline__ unsigned short f2bf(float x) {
    union { __hip_bfloat16 h; unsigned short u; } c;
    c.h = __float2bfloat16(x);
    return c.u;
}

__global__ __launch_bounds__(256) void to_bf16(const float* __restrict__ src,
                                               unsigned short* __restrict__ dst,
                                               int n8) {
    const int i = blockIdx.x * 256 + threadIdx.x;
    if (i >= n8) return;
    const float4* s = (const float4*)src + (size_t)i * 2;
    float4 a = s[0], b = s[1];
    union { unsigned short u[8]; uint4 v; } p;
    p.u[0] = f2bf(a.x); p.u[1] = f2bf(a.y); p.u[2] = f2bf(a.z); p.u[3] = f2bf(a.w);
    p.u[4] = f2bf(b.x); p.u[5] = f2bf(b.y); p.u[6] = f2bf(b.z); p.u[7] = f2bf(b.w);
    *(uint4*)(dst + (size_t)i * 8) = p.v;
}

// ---------------- exact numpy pairwise |row|^2 ----------------
__device__ __forceinline__ float np_pairwise_sq256(const float* a) {
    float res[2];
    #pragma unroll
    for (int b = 0; b < 2; ++b) {
        float r[8];
        #pragma unroll
        for (int j = 0; j < 8; ++j) r[j] = 0.f;
        #pragma unroll
        for (int m = 0; m < 16; ++m) {
            const int base = b * 128 + m * 8;
            #pragma unroll
            for (int j = 0; j < 8; ++j)
                r[j] = __fadd_rn(r[j], __fmul_rn(a[base + j], a[base + j]));
        }
        res[b] = __fadd_rn(__fadd_rn(__fadd_rn(r[0], r[1]), __fadd_rn(r[2], r[3])),
                           __fadd_rn(__fadd_rn(r[4], r[5]), __fadd_rn(r[6], r[7])));
    }
    return __fadd_rn(res[0], res[1]);
}

__global__ __launch_bounds__(256) void rownorm_np(const float* __restrict__ x,
                                                  float* __restrict__ out, int nrows) {
    const int row = blockIdx.x * 256 + threadIdx.x;
    if (row >= nrows) return;
    float a[256];
    const float4* p = (const float4*)(x + (size_t)row * D);
    #pragma unroll
    for (int k4 = 0; k4 < 64; ++k4) {
        float4 v = p[k4];
        a[k4 * 4 + 0] = v.x; a[k4 * 4 + 1] = v.y;
        a[k4 * 4 + 2] = v.z; a[k4 * 4 + 3] = v.w;
    }
    out[row] = np_pairwise_sq256(a);
}

// ---------------- bf16 MFMA screen (proven; + m1 store) ----------------
__global__ __launch_bounds__(256, 2) void vq_screen(const unsigned short* __restrict__ zbf,
                                                    const unsigned short* __restrict__ wbf,
                                                    const float* __restrict__ Cn,
                                                    int* __restrict__ idx_out,
                                                    int* __restrict__ flagged,
                                                    int* __restrict__ cnt,
                                                    float* __restrict__ m1_out) {
    __shared__ unsigned short zT[128 * 64];
    __shared__ unsigned short wT[128 * 64];
    __shared__ float Cs[1024];
    __shared__ float rm1s[2][128];
    __shared__ float rm2s[2][128];
    __shared__ int   ris[2][128];

    const int t    = threadIdx.x;
    const int wv   = t >> 6;          // wave 0..3
    const int l    = t & 63;
    const int wm   = wv >> 1;         // row half
    const int wn   = wv & 1;          // col half
    const int m    = l & 15;
    const int quad = l >> 4;
    const int row0 = blockIdx.x * 128;

    for (int i = t; i < 1024; i += 256) Cs[i] = Cn[i];

    float m1[4][4], m2[4][4];
    int   bi[4][4];
    #pragma unroll
    for (int mi = 0; mi < 4; ++mi)
        #pragma unroll
        for (int r = 0; r < 4; ++r) { m1[mi][r] = FLT_MAX; m2[mi][r] = FLT_MAX; bi[mi][r] = 0; }

    const int sr  = t & 127;          // staging row
    const int ssw = sr & 7;           // staging swizzle

    for (int nb = 0; nb < 8; ++nb) {
        f32x4 acc[4][4];
        #pragma unroll
        for (int mi = 0; mi < 4; ++mi)
            #pragma unroll
            for (int ni = 0; ni < 4; ++ni) acc[mi][ni] = (f32x4){0.f, 0.f, 0.f, 0.f};

        for (int ks = 0; ks < 4; ++ks) {
            __syncthreads();
            {
                const unsigned short* src = (t < 128)
                    ? zbf + ((size_t)(row0 + sr) * D + ks * 64)
                    : wbf + ((size_t)(nb * 128 + sr) * D + ks * 64);
                unsigned short* dst = (t < 128) ? &zT[sr * 64] : &wT[sr * 64];
                #pragma unroll
                for (int c = 0; c < 8; ++c) {
                    uint4 v = *(const uint4*)(src + c * 8);
                    *(uint4*)(dst + ((c ^ ssw) * 8)) = v;
                }
            }
            __syncthreads();
            #pragma unroll
            for (int kk = 0; kk < 2; ++kk) {
                short8 a[4], b[4];
                const int ch = kk * 4 + quad;
                #pragma unroll
                for (int mi = 0; mi < 4; ++mi) {
                    const int rr = wm * 64 + mi * 16 + m;
                    a[mi] = *(const short8*)&zT[rr * 64 + ((ch ^ (m & 7)) * 8)];
                }
                #pragma unroll
                for (int ni = 0; ni < 4; ++ni) {
                    const int rr = wn * 64 + ni * 16 + m;
                    b[ni] = *(const short8*)&wT[rr * 64 + ((ch ^ (m & 7)) * 8)];
                }
                #pragma unroll
                for (int mi = 0; mi < 4; ++mi)
                    #pragma unroll
                    for (int ni = 0; ni < 4; ++ni)
                        acc[mi][ni] = __builtin_amdgcn_mfma_f32_16x16x32_bf16(
                            a[mi], b[ni], acc[mi][ni], 0, 0, 0);
            }
        }
        #pragma unroll
        for (int ni = 0; ni < 4; ++ni) {
            const int code = nb * 128 + wn * 64 + ni * 16 + m;
            const float c  = Cs[code];
            #pragma unroll
            for (int mi = 0; mi < 4; ++mi)
                #pragma unroll
                for (int r = 0; r < 4; ++r) {
                    const float v = fmaf(-2.0f, acc[mi][ni][r], c);
                    if (v < m1[mi][r]) { m2[mi][r] = m1[mi][r]; m1[mi][r] = v; bi[mi][r] = code; }
                    else if (v < m2[mi][r]) m2[mi][r] = v;
                }
        }
    }

    #pragma unroll
    for (int mi = 0; mi < 4; ++mi)
        #pragma unroll
        for (int r = 0; r < 4; ++r) {
            float a1 = m1[mi][r], a2 = m2[mi][r];
            int   ai = bi[mi][r];
            #pragma unroll
            for (int off = 1; off <= 8; off <<= 1) {
                float o1 = __shfl_xor(a1, off, 64);
                float o2 = __shfl_xor(a2, off, 64);
                int   oi = __shfl_xor(ai, off, 64);
                float n2 = fminf(a2, o2);
                if (o1 < a1) { n2 = fminf(n2, a1); a1 = o1; ai = oi; }
                else n2 = fminf(n2, o1);
                a2 = n2;
            }
            m1[mi][r] = a1; m2[mi][r] = a2; bi[mi][r] = ai;
        }

    if (m == 0) {
        #pragma unroll
        for (int mi = 0; mi < 4; ++mi)
            #pragma unroll
            for (int r = 0; r < 4; ++r) {
                const int rl = wm * 64 + mi * 16 + quad * 4 + r;
                rm1s[wn][rl] = m1[mi][r];
                rm2s[wn][rl] = m2[mi][r];
                ris[wn][rl]  = bi[mi][r];
            }
    }
    __syncthreads();
    if (t < 128) {
        float a1 = rm1s[0][t], a2 = rm2s[0][t];
        int   ai = ris[0][t];
        const float o1 = rm1s[1][t], o2 = rm2s[1][t];
        const int   oi = ris[1][t];
        float n2 = fminf(a2, o2);
        if (o1 < a1) { n2 = fminf(n2, a1); a1 = o1; ai = oi; }
        else n2 = fminf(n2, o1);
        a2 = n2;
        const int row = row0 + t;
        idx_out[row] = ai;
        m1_out[row]  = a1;
        if (a2 - a1 < TAU_SCREEN) {
            int p = atomicAdd(cnt, 1);
            flagged[p] = row;
        }
    }
}

// ---------------- candidate emit: flagged rows x all codes (bf16 MFMA) ----------------
// Job = (tile of 128 gathered flagged rows) x (one 128-code n-block); grid-stride.
// Identical MFMA pipeline to vq_screen (bitwise-same scores); emits pairs
// (row,code) with v < m1g[row]+TAU. Winner self-includes (v(i1)==m1, TAU>0).
__global__ __launch_bounds__(256, 2) void vq_cand(const unsigned short* __restrict__ zbf,
                                                  const unsigned short* __restrict__ wbf,
                                                  const float* __restrict__ Cn,
                                                  const float* __restrict__ m1g,
                                                  const int* __restrict__ flagged,
                                                  const int* __restrict__ cnt,
                                                  uint32_t* __restrict__ pairs,
                                                  int* __restrict__ pcnt) {
    __shared__ unsigned short zT[128 * 64];
    __shared__ unsigned short wT[128 * 64];
    __shared__ int rows_s[128];

    const int t    = threadIdx.x;
    const int wv   = t >> 6;
    const int l    = t & 63;
    const int wm   = wv >> 1;
    const int wn   = wv & 1;
    const int m    = l & 15;
    const int quad = l >> 4;
    const int sr   = t & 127;
    const int ssw  = sr & 7;

    const int n  = *cnt;
    const int nt = (n + 127) >> 7;

    for (int job = blockIdx.x; job < nt * 8; job += gridDim.x) {
        const int tile = job >> 3;
        const int nb   = job & 7;
        __syncthreads();                     // LDS reuse guard
        if (t < 128) {
            const int fi = tile * 128 + t;
            rows_s[t] = (fi < n) ? flagged[fi] : -1;
        }
        __syncthreads();

        f32x4 acc[4][4];
        #pragma unroll
        for (int mi = 0; mi < 4; ++mi)
            #pragma unroll
            for (int ni = 0; ni < 4; ++ni) acc[mi][ni] = (f32x4){0.f, 0.f, 0.f, 0.f};

        for (int ks = 0; ks < 4; ++ks) {
            __syncthreads();
            {
                const int zr = rows_s[sr] < 0 ? 0 : rows_s[sr];
                const unsigned short* src = (t < 128)
                    ? zbf + ((size_t)zr * D + ks * 64)
                    : wbf + ((size_t)(nb * 128 + sr) * D + ks * 64);
                unsigned short* dst = (t < 128) ? &zT[sr * 64] : &wT[sr * 64];
                #pragma unroll
                for (int c = 0; c < 8; ++c) {
                    uint4 v = *(const uint4*)(src + c * 8);
                    *(uint4*)(dst + ((c ^ ssw) * 8)) = v;
                }
            }
            __syncthreads();
            #pragma unroll
            for (int kk = 0; kk < 2; ++kk) {
                short8 a[4], b[4];
                const int ch = kk * 4 + quad;
                #pragma unroll
                for (int mi = 0; mi < 4; ++mi) {
                    const int rr = wm * 64 + mi * 16 + m;
                    a[mi] = *(const short8*)&zT[rr * 64 + ((ch ^ (m & 7)) * 8)];
                }
                #pragma unroll
                for (int ni = 0; ni < 4; ++ni) {
                    const int rr = wn * 64 + ni * 16 + m;
                    b[ni] = *(const short8*)&wT[rr * 64 + ((ch ^ (m & 7)) * 8)];
                }
                #pragma unroll
                for (int mi = 0; mi < 4; ++mi)
                    #pragma unroll
                    for (int ni = 0; ni < 4; ++ni)
                        acc[mi][ni] = __builtin_amdgcn_mfma_f32_16x16x32_bf16(
                            a[mi], b[ni], acc[mi][ni], 0, 0, 0);
            }
        }

        // epilogue: emit candidate pairs. Rows of acc[mi][*][r]: wm*64+mi*16+quad*4+r.
        int   rowid[4][4];
        float thr[4][4];
        #pragma unroll
        for (int mi = 0; mi < 4; ++mi)
            #pragma unroll
            for (int r = 0; r < 4; ++r) {
                const int rl = wm * 64 + mi * 16 + quad * 4 + r;
                const int ri = rows_s[rl];
                rowid[mi][r] = ri;
                thr[mi][r]   = (ri >= 0) ? m1g[ri] + TAU_SCREEN : -FLT_MAX;
            }
        #pragma unroll
        for (int ni = 0; ni < 4; ++ni) {
            const int code = nb * 128 + wn * 64 + ni * 16 + m;
            const float c  = Cn[code];
            #pragma unroll
            for (int mi = 0; mi < 4; ++mi)
                #pragma unroll
                for (int r = 0; r < 4; ++r) {
                    const float v = fmaf(-2.0f, acc[mi][ni][r], c);
                    if (v < thr[mi][r]) {
                        const int p = atomicAdd(pcnt, 1);
                        if (p < MAXPAIRS)
                            pairs[p] = ((uint32_t)rowid[mi][r] << 16) | (uint32_t)code;
                    }
                }
        }
    }
}

// ---------------- exact eval: one lane per (row,code) pair ----------------
// Bit-exact numpy-fp32 chain: A = pairwise(|z|^2) (r[j] over m asc, tree),
// B = sequential-k fma, d = fl(fl(A-2B)+C). atomicMin packed (ordered-d, code):
// smallest d wins, ties -> smallest code = numpy first-index.
__global__ __launch_bounds__(256) void vq_exact(const float* __restrict__ z,
                                                const float* __restrict__ w,
                                                const float* __restrict__ Cn,
                                                const uint32_t* __restrict__ pairs,
                                                const int* __restrict__ pcnt,
                                                unsigned long long* __restrict__ packed) {
    const int np0 = *pcnt;
    const int np  = np0 < MAXPAIRS ? np0 : MAXPAIRS;
    for (int g = blockIdx.x * 256 + threadIdx.x; g < np; g += gridDim.x * 256) {
        const uint32_t pr = pairs[g];
        const int row  = (int)(pr >> 16);
        const int code = (int)(pr & 0xffffu);
        const float4* zp = (const float4*)(z + (size_t)row * D);
        const float4* wp = (const float4*)(w + (size_t)code * D);
        float B = 0.f;
        float res[2];
        #pragma unroll
        for (int b = 0; b < 2; ++b) {
            float r[8];
            #pragma unroll
            for (int j = 0; j < 8; ++j) r[j] = 0.f;
            #pragma unroll 4
            for (int mm = 0; mm < 16; ++mm) {
                const float4 z0 = zp[b * 32 + mm * 2];
                const float4 z1 = zp[b * 32 + mm * 2 + 1];
                const float4 w0 = wp[b * 32 + mm * 2];
                const float4 w1 = wp[b * 32 + mm * 2 + 1];
                r[0] = __fadd_rn(r[0], __fmul_rn(z0.x, z0.x));
                r[1] = __fadd_rn(r[1], __fmul_rn(z0.y, z0.y));
                r[2] = __fadd_rn(r[2], __fmul_rn(z0.z, z0.z));
                r[3] = __fadd_rn(r[3], __fmul_rn(z0.w, z0.w));
                r[4] = __fadd_rn(r[4], __fmul_rn(z1.x, z1.x));
                r[5] = __fadd_rn(r[5], __fmul_rn(z1.y, z1.y));
                r[6] = __fadd_rn(r[6], __fmul_rn(z1.z, z1.z));
                r[7] = __fadd_rn(r[7], __fmul_rn(z1.w, z1.w));
                B = fmaf(z0.x, w0.x, B); B = fmaf(z0.y, w0.y, B);
                B = fmaf(z0.z, w0.z, B); B = fmaf(z0.w, w0.w, B);
                B = fmaf(z1.x, w1.x, B); B = fmaf(z1.y, w1.y, B);
                B = fmaf(z1.z, w1.z, B); B = fmaf(z1.w, w1.w, B);
            }
            res[b] = __fadd_rn(__fadd_rn(__fadd_rn(r[0], r[1]), __fadd_rn(r[2], r[3])),
                               __fadd_rn(__fadd_rn(r[4], r[5]), __fadd_rn(r[6], r[7])));
        }
        const float A = __fadd_rn(res[0], res[1]);
        const float d = __fadd_rn(__fsub_rn(A, __fmul_rn(2.0f, B)), Cn[code]);
        const uint32_t bits = __float_as_uint(d);
        const uint32_t ord  = (bits & 0x80000000u) ? ~bits : (bits | 0x80000000u);
        const unsigned long long key =
            ((unsigned long long)ord << 32) | (unsigned long long)(uint32_t)code;
        atomicMin(&packed[row], key);
    }
}

// ---------------- unpack refined indices ----------------
__global__ __launch_bounds__(256) void vq_unpack(const int* __restrict__ flagged,
                                                 const int* __restrict__ cnt,
                                                 const unsigned long long* __restrict__ packed,
                                                 int* __restrict__ idx) {
    const int n = *cnt;
    for (int g = blockIdx.x * 256 + threadIdx.x; g < n; g += gridDim.x * 256) {
        const int row = flagged[g];
        idx[row] = (int)(packed[row] & 0xffffffffull);
    }
}

// ---------------- gather ----------------
__global__ __launch_bounds__(256) void vq_gather(const float* __restrict__ w,
                                                 const int* __restrict__ idx,
                                                 float* __restrict__ outq,
                                                 float* __restrict__ outi) {
    const int t    = threadIdx.x;
    const int lane = t & 63;
    const int sub  = t >> 6;
    const int row0 = blockIdx.x * 128;
    #pragma unroll 4
    for (int it = 0; it < 32; ++it) {
        const int row = row0 + it * 4 + sub;
        const int j   = idx[row];
        ((float4*)outq)[(size_t)row * 64 + lane] = ((const float4*)w)[(size_t)j * 64 + lane];
        if (lane == 0) outi[row] = (float)j;
    }
}

extern "C" void kernel_launch(void* const* d_in, const int* in_sizes, int n_in,
                              void* d_out, int out_size, void* d_ws, size_t ws_size,
                              hipStream_t stream) {
    const float* z = (const float*)d_in[0];
    const float* w = (const float*)d_in[1];
    float* outq = (float*)d_out;
    float* outi = outq + (size_t)NROWS * D;

    // scratch inside d_out (all dead before vq_gather):
    //   zbf   [0, 32MB)        bf16 z (dead after screen/cand)
    //   wbf   [32MB, 32.5MB)   bf16 w
    //   Cn    [32.5MB, +4KB)   |w|^2
    //   m1g   [35MB, +256KB)   per-row screen min1
    //   packed[35.5MB, +512KB) per-row (ordered-d, code) u64
    //   pairs [36MB, ...)      candidate (row<<16|code) u32, cap MAXPAIRS
    unsigned short*     zbf    = (unsigned short*)d_out;
    unsigned short*     wbf    = (unsigned short*)((char*)d_out + 33554432);
    float*              Cn     = (float*)((char*)d_out + 34078720);
    float*              m1g    = (float*)((char*)d_out + 36700160);
    unsigned long long* packed = (unsigned long long*)((char*)d_out + 37224448);
    uint32_t*           pairs  = (uint32_t*)((char*)d_out + 37748736);

    char* ws      = (char*)d_ws;
    int*  idx     = (int*)ws;
    int*  flagged = (int*)(ws + 262144);
    int*  cnt     = (int*)(ws + 524288);
    int*  pcnt    = (int*)(ws + 524292);

    init_ws<<<256, 256, 0, stream>>>(cnt, pcnt, packed);
    to_bf16<<<NROWS * D / 8 / 256, 256, 0, stream>>>(z, zbf, NROWS * D / 8);
    to_bf16<<<CODES * D / 8 / 256, 256, 0, stream>>>(w, wbf, CODES * D / 8);
    rownorm_np<<<(CODES + 255) / 256, 256, 0, stream>>>(w, Cn, CODES);
    vq_screen<<<NROWS / 128, 256, 0, stream>>>(zbf, wbf, Cn, idx, flagged, cnt, m1g);
    vq_cand<<<512, 256, 0, stream>>>(zbf, wbf, Cn, m1g, flagged, cnt, pairs, pcnt);
    vq_exact<<<256, 256, 0, stream>>>(z, w, Cn, pairs, pcnt, packed);
    vq_unpack<<<64, 256, 0, stream>>>(flagged, cnt, packed, idx);
    vq_gather<<<NROWS / 128, 256, 0, stream>>>(w, idx, outq, outi);
}

// Round 4
// 309.304 us; speedup vs baseline: 1.9395x; 1.0665x over previous
//
#include <hip/hip_runtime.h>
#include <hip/hip_bf16.h>
#include <stdint.h>
#include <float.h>

// VQ quantize: z[65536,256] f32, weight[1024,256] f32.
// ref (numpy fp32): d = fl32(fl32(A - 2*B) + C); idx = argmax(-d) (first-index ties).
// Outputs (float32, concat): quantized [65536*256], indices [65536].
//
// Pipeline:
//   1) vq_prep: fused {init counters/packed, z->bf16, w->bf16, Cn=|w|^2 exact}
//   2) vq_screen: bf16 MFMA 16x16x32 GEMM (scores = C - 2*z.wT), per-row
//      (min1,min2,idx); rows with margin < TAU flagged (n ~ 4700, 7%); m1 stored.
//      R7: 2-phase async pipeline -- double-buffered z/w LDS tiles staged via
//      global_load_lds (pre-swizzled global source, linear LDS dest, m173),
//      issue stage(s+1) -> compute(s) -> vmcnt(0)+barrier. Old structure had
//      staging latency between back-to-back barriers => MfmaUtil 13%.
//   3) vq_cand: same pipelined MFMA on gathered flagged rows (z staged once
//      per tile, nb inside); emits (row,code) pairs with score < m1+TAU.
//      Bitwise-same scores as screen (identical MFMA order) => winner self-includes.
//   4) vq_exact: one lane per pair; bit-exact numpy-fp32 chain (pairwise A,
//      sequential-k fma B -- proven absmax=0); atomicMin packed (ordered-d, code).
//   5) vq_unpack, 6) vq_gather.

constexpr int NROWS = 65536;
constexpr int D     = 256;
constexpr int CODES = 1024;

constexpr float TAU_SCREEN = 2.5e-4f;
constexpr int   MAXPAIRS   = 7000000;

typedef __attribute__((ext_vector_type(8))) short short8;   // 8 bf16 = 4 VGPR
typedef __attribute__((ext_vector_type(4))) float f32x4;

// global -> LDS async 16B/lane: per-lane global src, wave-uniform LDS base,
// HW writes lane l -> base + l*16 (m97/m104 semantics).
__device__ __forceinline__ void gl2lds16(const unsigned short* g, unsigned short* l) {
    __builtin_amdgcn_global_load_lds(
        (const __attribute__((address_space(1))) void*)g,
        (__attribute__((address_space(3))) void*)l, 16, 0, 0);
}

// ---------------- fp32 -> bf16 (RNE) ----------------
__device__ __forceinline__ unsigned short f2bf(float x) {
    union { __hip_bfloat16 h; unsigned short u; } c;
    c.h = __float2bfloat16(x);
    return c.u;
}

__device__ __forceinline__ void cvt8(const float* __restrict__ src,
                                     unsigned short* __restrict__ dst, int i) {
    const float4* s = (const float4*)src + (size_t)i * 2;
    float4 a = s[0], b = s[1];
    union { unsigned short u[8]; uint4 v; } p;
    p.u[0] = f2bf(a.x); p.u[1] = f2bf(a.y); p.u[2] = f2bf(a.z); p.u[3] = f2bf(a.w);
    p.u[4] = f2bf(b.x); p.u[5] = f2bf(b.y); p.u[6] = f2bf(b.z); p.u[7] = f2bf(b.w);
    *(uint4*)(dst + (size_t)i * 8) = p.v;
}

// ---------------- fused prep ----------------
// blocks [0,8192): z->bf16 | [8192,8320): w->bf16 | [8320,8324): rownorm |
// [8324,8580): packed init + counters. rownorm is register-lean but in the
// EXACT numpy pairwise order (r[j] over ascending m, 8-way tree, halves added).
__global__ __launch_bounds__(256) void vq_prep(const float* __restrict__ z,
                                               unsigned short* __restrict__ zbf,
                                               const float* __restrict__ w,
                                               unsigned short* __restrict__ wbf,
                                               float* __restrict__ Cn,
                                               int* __restrict__ cnt,
                                               int* __restrict__ pcnt,
                                               unsigned long long* __restrict__ packed) {
    const int b = blockIdx.x;
    const int t = threadIdx.x;
    if (b < 8192) {
        cvt8(z, zbf, b * 256 + t);
    } else if (b < 8320) {
        cvt8(w, wbf, (b - 8192) * 256 + t);
    } else if (b < 8324) {
        const int row = (b - 8320) * 256 + t;
        const float4* p = (const float4*)(w + (size_t)row * D);
        float res[2];
        #pragma unroll
        for (int h = 0; h < 2; ++h) {
            float r[8];
            #pragma unroll
            for (int j = 0; j < 8; ++j) r[j] = 0.f;
            #pragma unroll 4
            for (int mm = 0; mm < 16; ++mm) {
                const float4 v0 = p[h * 32 + mm * 2];
                const float4 v1 = p[h * 32 + mm * 2 + 1];
                r[0] = __fadd_rn(r[0], __fmul_rn(v0.x, v0.x));
                r[1] = __fadd_rn(r[1], __fmul_rn(v0.y, v0.y));
                r[2] = __fadd_rn(r[2], __fmul_rn(v0.z, v0.z));
                r[3] = __fadd_rn(r[3], __fmul_rn(v0.w, v0.w));
                r[4] = __fadd_rn(r[4], __fmul_rn(v1.x, v1.x));
                r[5] = __fadd_rn(r[5], __fmul_rn(v1.y, v1.y));
                r[6] = __fadd_rn(r[6], __fmul_rn(v1.z, v1.z));
                r[7] = __fadd_rn(r[7], __fmul_rn(v1.w, v1.w));
            }
            res[h] = __fadd_rn(__fadd_rn(__fadd_rn(r[0], r[1]), __fadd_rn(r[2], r[3])),
                               __fadd_rn(__fadd_rn(r[4], r[5]), __fadd_rn(r[6], r[7])));
        }
        Cn[row] = __fadd_rn(res[0], res[1]);
    } else {
        const int i = (b - 8324) * 256 + t;
        packed[i] = ~0ull;
        if (i == 0) { *cnt = 0; *pcnt = 0; }
    }
}

// ---------------- bf16 MFMA screen (R7: 2-phase async pipeline) ----------------
// 128 rows x 1024 codes per block; 32 steps (nb-major, ks-minor), dbuf LDS.
// LDS layout per buffer: [row][64k] bf16, 16B chunk at position p holds global
// chunk p ^ (row&7) (same as proven read path). Staged with LINEAR LDS dest +
// pre-swizzled global source: lane l -> row base+ (l>>3), pos l&7, src chunk
// (l&7)^(l>>3). Waves 0,1 stage z halves; waves 2,3 stage w halves.
__global__ __launch_bounds__(256, 2) void vq_screen(const unsigned short* __restrict__ zbf,
                                                    const unsigned short* __restrict__ wbf,
                                                    const float* __restrict__ Cn,
                                                    int* __restrict__ idx_out,
                                                    int* __restrict__ flagged,
                                                    int* __restrict__ cnt,
                                                    float* __restrict__ m1_out) {
    __shared__ unsigned short zT[2][128 * 64];
    __shared__ unsigned short wT[2][128 * 64];
    __shared__ float Cs[1024];
    __shared__ float rm1s[2][128];
    __shared__ float rm2s[2][128];
    __shared__ int   ris[2][128];

    const int t    = threadIdx.x;
    const int wv   = t >> 6;          // wave 0..3
    const int l    = t & 63;
    const int wm   = wv >> 1;         // row half
    const int wn   = wv & 1;          // col half
    const int m    = l & 15;
    const int quad = l >> 4;
    const int row0 = blockIdx.x * 128;

    // staging geometry
    const int  srow8   = l >> 3;                       // row within 8-row group
    const int  schunk  = (l & 7) ^ srow8;              // pre-swizzled src chunk
    const size_t laneoff = (size_t)srow8 * D + schunk * 8;   // elems
    const bool stz   = (wv < 2);
    const int  sbase = (wv & 1) * 64;                  // tile-row base (0/64)

    for (int i = t; i < 1024; i += 256) Cs[i] = Cn[i];

    float m1[4][4], m2[4][4];
    int   bi[4][4];
    f32x4 acc[4][4];
    #pragma unroll
    for (int mi = 0; mi < 4; ++mi)
        #pragma unroll
        for (int r = 0; r < 4; ++r) {
            m1[mi][r] = FLT_MAX; m2[mi][r] = FLT_MAX; bi[mi][r] = 0;
            acc[mi][r] = (f32x4){0.f, 0.f, 0.f, 0.f};
        }

    // stage step s (nb=s>>2, ks=s&3) into buffer buf: 8 global_load_lds/wave
    #define STAGE(s_, buf_) do {                                                   \
        const int nb_ = (s_) >> 2, ks_ = (s_) & 3;                                 \
        unsigned short* ldsb_ = stz ? &zT[buf_][sbase * 64] : &wT[buf_][sbase * 64];\
        const unsigned short* gb_ = stz                                            \
            ? zbf + (size_t)(row0 + sbase) * D + ks_ * 64                          \
            : wbf + (size_t)(nb_ * 128 + sbase) * D + ks_ * 64;                    \
        _Pragma("unroll")                                                          \
        for (int i_ = 0; i_ < 8; ++i_)                                             \
            gl2lds16(gb_ + (size_t)i_ * 8 * D + laneoff, ldsb_ + i_ * 512);        \
    } while (0)

    STAGE(0, 0);
    asm volatile("s_waitcnt vmcnt(0)" ::: "memory");
    __syncthreads();

    for (int s = 0; s < 32; ++s) {
        const int cur = s & 1;
        if (s + 1 < 32) STAGE(s + 1, cur ^ 1);
        #pragma unroll
        for (int kk = 0; kk < 2; ++kk) {
            short8 a[4], b[4];
            const int ch = kk * 4 + quad;
            const int co = (ch ^ (m & 7)) * 8;
            #pragma unroll
            for (int mi = 0; mi < 4; ++mi)
                a[mi] = *(const short8*)&zT[cur][(wm * 64 + mi * 16 + m) * 64 + co];
            #pragma unroll
            for (int ni = 0; ni < 4; ++ni)
                b[ni] = *(const short8*)&wT[cur][(wn * 64 + ni * 16 + m) * 64 + co];
            #pragma unroll
            for (int mi = 0; mi < 4; ++mi)
                #pragma unroll
                for (int ni = 0; ni < 4; ++ni)
                    acc[mi][ni] = __builtin_amdgcn_mfma_f32_16x16x32_bf16(
                        a[mi], b[ni], acc[mi][ni], 0, 0, 0);
        }
        if ((s & 3) == 3) {                    // nb complete: min-update + reset acc
            const int nb = s >> 2;
            #pragma unroll
            for (int ni = 0; ni < 4; ++ni) {
                const int code = nb * 128 + wn * 64 + ni * 16 + m;
                const float c  = Cs[code];
                #pragma unroll
                for (int mi = 0; mi < 4; ++mi)
                    #pragma unroll
                    for (int r = 0; r < 4; ++r) {
                        const float v = fmaf(-2.0f, acc[mi][ni][r], c);
                        if (v < m1[mi][r]) { m2[mi][r] = m1[mi][r]; m1[mi][r] = v; bi[mi][r] = code; }
                        else if (v < m2[mi][r]) m2[mi][r] = v;
                        acc[mi][ni][r] = 0.f;
                    }
            }
        }
        asm volatile("s_waitcnt vmcnt(0)" ::: "memory");
        __syncthreads();
    }

    // reduce across the 16 col-lanes (xor 1,2,4,8 varies l&15 only).
    #pragma unroll
    for (int mi = 0; mi < 4; ++mi)
        #pragma unroll
        for (int r = 0; r < 4; ++r) {
            float a1 = m1[mi][r], a2 = m2[mi][r];
            int   ai = bi[mi][r];
            #pragma unroll
            for (int off = 1; off <= 8; off <<= 1) {
                float o1 = __shfl_xor(a1, off, 64);
                float o2 = __shfl_xor(a2, off, 64);
                int   oi = __shfl_xor(ai, off, 64);
                float n2 = fminf(a2, o2);
                if (o1 < a1) { n2 = fminf(n2, a1); a1 = o1; ai = oi; }
                else n2 = fminf(n2, o1);
                a2 = n2;
            }
            m1[mi][r] = a1; m2[mi][r] = a2; bi[mi][r] = ai;
        }

    if (m == 0) {
        #pragma unroll
        for (int mi = 0; mi < 4; ++mi)
            #pragma unroll
            for (int r = 0; r < 4; ++r) {
                const int rl = wm * 64 + mi * 16 + quad * 4 + r;
                rm1s[wn][rl] = m1[mi][r];
                rm2s[wn][rl] = m2[mi][r];
                ris[wn][rl]  = bi[mi][r];
            }
    }
    __syncthreads();
    if (t < 128) {
        float a1 = rm1s[0][t], a2 = rm2s[0][t];
        int   ai = ris[0][t];
        const float o1 = rm1s[1][t], o2 = rm2s[1][t];
        const int   oi = ris[1][t];
        float n2 = fminf(a2, o2);
        if (o1 < a1) { n2 = fminf(n2, a1); a1 = o1; ai = oi; }
        else n2 = fminf(n2, o1);
        a2 = n2;
        const int row = row0 + t;
        idx_out[row] = ai;
        m1_out[row]  = a1;
        if (a2 - a1 < TAU_SCREEN) {
            int p = atomicAdd(cnt, 1);
            flagged[p] = row;
        }
    }
    #undef STAGE
}

// ---------------- candidate emit (R7: same pipeline, gathered rows) ----------------
// Job = one tile of 128 gathered flagged rows x ALL codes (nb inside).
// Bitwise-identical MFMA order to vq_screen; emits (row,code) with v < m1+TAU.
__global__ __launch_bounds__(256, 2) void vq_cand(const unsigned short* __restrict__ zbf,
                                                  const unsigned short* __restrict__ wbf,
                                                  const float* __restrict__ Cn,
                                                  const float* __restrict__ m1g,
                                                  const int* __restrict__ flagged,
                                                  const int* __restrict__ cnt,
                                                  uint32_t* __restrict__ pairs,
                                                  int* __restrict__ pcnt) {
    __shared__ unsigned short zT[2][128 * 64];
    __shared__ unsigned short wT[2][128 * 64];
    __shared__ int rows_s[128];

    const int t    = threadIdx.x;
    const int wv   = t >> 6;
    const int l    = t & 63;
    const int wm   = wv >> 1;
    const int wn   = wv & 1;
    const int m    = l & 15;
    const int quad = l >> 4;

    const int  srow8   = l >> 3;
    const int  schunk  = (l & 7) ^ srow8;
    const size_t laneoff_w = (size_t)srow8 * D + schunk * 8;
    const bool stz   = (wv < 2);
    const int  sbase = (wv & 1) * 64;

    const int n  = *cnt;
    const int nt = (n + 127) >> 7;

    for (int tile = blockIdx.x; tile < nt; tile += gridDim.x) {
        __syncthreads();                     // LDS reuse guard
        if (t < 128) {
            const int fi = tile * 128 + t;
            rows_s[t] = (fi < n) ? flagged[fi] : -1;
        }
        __syncthreads();

        // per-lane staging rows (z waves) and emission thresholds
        int zrow[8];
        #pragma unroll
        for (int i = 0; i < 8; ++i) {
            const int rr = rows_s[sbase + i * 8 + srow8];
            zrow[i] = rr < 0 ? 0 : rr;
        }
        int   rowid[4][4];
        float thr[4][4];
        #pragma unroll
        for (int mi = 0; mi < 4; ++mi)
            #pragma unroll
            for (int r = 0; r < 4; ++r) {
                const int rl = wm * 64 + mi * 16 + quad * 4 + r;
                const int ri = rows_s[rl];
                rowid[mi][r] = ri;
                thr[mi][r]   = (ri >= 0) ? m1g[ri] + TAU_SCREEN : -FLT_MAX;
            }

        f32x4 acc[4][4];
        #pragma unroll
        for (int mi = 0; mi < 4; ++mi)
            #pragma unroll
            for (int ni = 0; ni < 4; ++ni) acc[mi][ni] = (f32x4){0.f, 0.f, 0.f, 0.f};

        #define STAGEC(s_, buf_) do {                                                 \
            const int nb_ = (s_) >> 2, ks_ = (s_) & 3;                                \
            if (stz) {                                                                \
                unsigned short* ldsb_ = &zT[buf_][sbase * 64];                        \
                _Pragma("unroll")                                                     \
                for (int i_ = 0; i_ < 8; ++i_)                                        \
                    gl2lds16(zbf + (size_t)zrow[i_] * D + ks_ * 64 + schunk * 8,      \
                             ldsb_ + i_ * 512);                                       \
            } else {                                                                  \
                unsigned short* ldsb_ = &wT[buf_][sbase * 64];                        \
                const unsigned short* gb_ =                                           \
                    wbf + (size_t)(nb_ * 128 + sbase) * D + ks_ * 64;                 \
                _Pragma("unroll")                                                     \
                for (int i_ = 0; i_ < 8; ++i_)                                        \
                    gl2lds16(gb_ + (size_t)i_ * 8 * D + laneoff_w, ldsb_ + i_ * 512); \
            }                                                                         \
        } while (0)

        STAGEC(0, 0);
        asm volatile("s_waitcnt vmcnt(0)" ::: "memory");
        __syncthreads();

        for (int s = 0; s < 32; ++s) {
            const int cur = s & 1;
            if (s + 1 < 32) STAGEC(s + 1, cur ^ 1);
            #pragma unroll
            for (int kk = 0; kk < 2; ++kk) {
                short8 a[4], b[4];
                const int ch = kk * 4 + quad;
                const int co = (ch ^ (m & 7)) * 8;
                #pragma unroll
                for (int mi = 0; mi < 4; ++mi)
                    a[mi] = *(const short8*)&zT[cur][(wm * 64 + mi * 16 + m) * 64 + co];
                #pragma unroll
                for (int ni = 0; ni < 4; ++ni)
                    b[ni] = *(const short8*)&wT[cur][(wn * 64 + ni * 16 + m) * 64 + co];
                #pragma unroll
                for (int mi = 0; mi < 4; ++mi)
                    #pragma unroll
                    for (int ni = 0; ni < 4; ++ni)
                        acc[mi][ni] = __builtin_amdgcn_mfma_f32_16x16x32_bf16(
                            a[mi], b[ni], acc[mi][ni], 0, 0, 0);
            }
            if ((s & 3) == 3) {
                const int nb = s >> 2;
                #pragma unroll
                for (int ni = 0; ni < 4; ++ni) {
                    const int code = nb * 128 + wn * 64 + ni * 16 + m;
                    const float c  = Cn[code];
                    #pragma unroll
                    for (int mi = 0; mi < 4; ++mi)
                        #pragma unroll
                        for (int r = 0; r < 4; ++r) {
                            const float v = fmaf(-2.0f, acc[mi][ni][r], c);
                            if (v < thr[mi][r]) {
                                const int p = atomicAdd(pcnt, 1);
                                if (p < MAXPAIRS)
                                    pairs[p] = ((uint32_t)rowid[mi][r] << 16) | (uint32_t)code;
                            }
                            acc[mi][ni][r] = 0.f;
                        }
                }
            }
            asm volatile("s_waitcnt vmcnt(0)" ::: "memory");
            __syncthreads();
        }
        #undef STAGEC
    }
}

// ---------------- exact eval: one lane per (row,code) pair ----------------
__global__ __launch_bounds__(256) void vq_exact(const float* __restrict__ z,
                                                const float* __restrict__ w,
                                                const float* __restrict__ Cn,
                                                const uint32_t* __restrict__ pairs,
                                                const int* __restrict__ pcnt,
                                                unsigned long long* __restrict__ packed) {
    const int np0 = *pcnt;
    const int np  = np0 < MAXPAIRS ? np0 : MAXPAIRS;
    for (int g = blockIdx.x * 256 + threadIdx.x; g < np; g += gridDim.x * 256) {
        const uint32_t pr = pairs[g];
        const int row  = (int)(pr >> 16);
        const int code = (int)(pr & 0xffffu);
        const float4* zp = (const float4*)(z + (size_t)row * D);
        const float4* wp = (const float4*)(w + (size_t)code * D);
        float B = 0.f;
        float res[2];
        #pragma unroll
        for (int b = 0; b < 2; ++b) {
            float r[8];
            #pragma unroll
            for (int j = 0; j < 8; ++j) r[j] = 0.f;
            #pragma unroll 4
            for (int mm = 0; mm < 16; ++mm) {
                const float4 z0 = zp[b * 32 + mm * 2];
                const float4 z1 = zp[b * 32 + mm * 2 + 1];
                const float4 w0 = wp[b * 32 + mm * 2];
                const float4 w1 = wp[b * 32 + mm * 2 + 1];
                r[0] = __fadd_rn(r[0], __fmul_rn(z0.x, z0.x));
                r[1] = __fadd_rn(r[1], __fmul_rn(z0.y, z0.y));
                r[2] = __fadd_rn(r[2], __fmul_rn(z0.z, z0.z));
                r[3] = __fadd_rn(r[3], __fmul_rn(z0.w, z0.w));
                r[4] = __fadd_rn(r[4], __fmul_rn(z1.x, z1.x));
                r[5] = __fadd_rn(r[5], __fmul_rn(z1.y, z1.y));
                r[6] = __fadd_rn(r[6], __fmul_rn(z1.z, z1.z));
                r[7] = __fadd_rn(r[7], __fmul_rn(z1.w, z1.w));
                B = fmaf(z0.x, w0.x, B); B = fmaf(z0.y, w0.y, B);
                B = fmaf(z0.z, w0.z, B); B = fmaf(z0.w, w0.w, B);
                B = fmaf(z1.x, w1.x, B); B = fmaf(z1.y, w1.y, B);
                B = fmaf(z1.z, w1.z, B); B = fmaf(z1.w, w1.w, B);
            }
            res[b] = __fadd_rn(__fadd_rn(__fadd_rn(r[0], r[1]), __fadd_rn(r[2], r[3])),
                               __fadd_rn(__fadd_rn(r[4], r[5]), __fadd_rn(r[6], r[7])));
        }
        const float A = __fadd_rn(res[0], res[1]);
        const float d = __fadd_rn(__fsub_rn(A, __fmul_rn(2.0f, B)), Cn[code]);
        const uint32_t bits = __float_as_uint(d);
        const uint32_t ord  = (bits & 0x80000000u) ? ~bits : (bits | 0x80000000u);
        const unsigned long long key =
            ((unsigned long long)ord << 32) | (unsigned long long)(uint32_t)code;
        atomicMin(&packed[row], key);
    }
}

// ---------------- unpack refined indices ----------------
__global__ __launch_bounds__(256) void vq_unpack(const int* __restrict__ flagged,
                                                 const int* __restrict__ cnt,
                                                 const unsigned long long* __restrict__ packed,
                                                 int* __restrict__ idx) {
    const int n = *cnt;
    for (int g = blockIdx.x * 256 + threadIdx.x; g < n; g += gridDim.x * 256) {
        const int row = flagged[g];
        idx[row] = (int)(packed[row] & 0xffffffffull);
    }
}

// ---------------- gather ----------------
__global__ __launch_bounds__(256) void vq_gather(const float* __restrict__ w,
                                                 const int* __restrict__ idx,
                                                 float* __restrict__ outq,
                                                 float* __restrict__ outi) {
    const int t    = threadIdx.x;
    const int lane = t & 63;
    const int sub  = t >> 6;
    const int row0 = blockIdx.x * 128;
    #pragma unroll 4
    for (int it = 0; it < 32; ++it) {
        const int row = row0 + it * 4 + sub;
        const int j   = idx[row];
        ((float4*)outq)[(size_t)row * 64 + lane] = ((const float4*)w)[(size_t)j * 64 + lane];
        if (lane == 0) outi[row] = (float)j;
    }
}

extern "C" void kernel_launch(void* const* d_in, const int* in_sizes, int n_in,
                              void* d_out, int out_size, void* d_ws, size_t ws_size,
                              hipStream_t stream) {
    const float* z = (const float*)d_in[0];
    const float* w = (const float*)d_in[1];
    float* outq = (float*)d_out;
    float* outi = outq + (size_t)NROWS * D;

    // scratch inside d_out (all dead before vq_gather):
    //   zbf   [0, 32MB)        bf16 z
    //   wbf   [32MB, 32.5MB)   bf16 w
    //   Cn    [32.5MB, +4KB)   |w|^2
    //   m1g   [35MB, +256KB)   per-row screen min1
    //   packed[35.5MB, +512KB) per-row (ordered-d, code) u64
    //   pairs [36MB, ...)      candidate (row<<16|code) u32, cap MAXPAIRS
    unsigned short*     zbf    = (unsigned short*)d_out;
    unsigned short*     wbf    = (unsigned short*)((char*)d_out + 33554432);
    float*              Cn     = (float*)((char*)d_out + 34078720);
    float*              m1g    = (float*)((char*)d_out + 36700160);
    unsigned long long* packed = (unsigned long long*)((char*)d_out + 37224448);
    uint32_t*           pairs  = (uint32_t*)((char*)d_out + 37748736);

    char* ws      = (char*)d_ws;
    int*  idx     = (int*)ws;
    int*  flagged = (int*)(ws + 262144);
    int*  cnt     = (int*)(ws + 524288);
    int*  pcnt    = (int*)(ws + 524292);

    vq_prep<<<8580, 256, 0, stream>>>(z, zbf, w, wbf, Cn, cnt, pcnt, packed);
    vq_screen<<<NROWS / 128, 256, 0, stream>>>(zbf, wbf, Cn, idx, flagged, cnt, m1g);
    vq_cand<<<512, 256, 0, stream>>>(zbf, wbf, Cn, m1g, flagged, cnt, pairs, pcnt);
    vq_exact<<<256, 256, 0, stream>>>(z, w, Cn, pairs, pcnt, packed);
    vq_unpack<<<64, 256, 0, stream>>>(flagged, cnt, packed, idx);
    vq_gather<<<NROWS / 128, 256, 0, stream>>>(w, idx, outq, outi);
}

// Round 6
// 292.589 us; speedup vs baseline: 2.0503x; 1.0571x over previous
//
#include <hip/hip_runtime.h>
#include <hip/hip_bf16.h>
#include <stdint.h>
#include <float.h>

// VQ quantize: z[65536,256] f32, weight[1024,256] f32.
// ref (numpy fp32): d = fl32(fl32(A - 2*B) + C); idx = argmax(-d) (first-index ties).
// Outputs (float32, concat): quantized [65536*256], indices [65536].
//
// Pipeline:
//   1) vq_prep: fused {init counters/packed, z->bf16, w->bf16, Cn=|w|^2 exact}
//   2) vq_screen: bf16 MFMA 16x16x32 GEMM (scores = C - 2*z.wT), per-row
//      (min1,min2,idx); rows with margin < TAU flagged (n ~ 4700, 7%); m1 stored.
//      R8: T4 counted-vmcnt pipeline -- STAGE(s+1); s_waitcnt vmcnt(8); raw
//      s_barrier; compute(s); raw s_barrier. vmcnt(8) retires all older loads
//      (in-order) while the new 8 stay in flight across compute.
//   3) vq_cand: (tile x nb) jobs (~296 active blocks), same counted-vmcnt
//      4-step pipeline; emits (row,code) with score < m1+TAU. Bitwise-same
//      scores as screen => winner self-includes.
//   4) vq_exact: one lane per pair; bit-exact numpy-fp32 chain (pairwise A,
//      sequential-k fma B -- proven absmax=0); atomicMin packed (ordered-d, code).
//   5) vq_unpack: MUST be a separate kernel (R5 crash: folding it into gather
//      raced -- gather's outq writes overwrite the packed region of d_out while
//      other blocks read it -> garbage index -> OOB fault). Scratch-in-d_out
//      invariant: ALL scratch dead before vq_gather launches.
//   6) vq_gather.

constexpr int NROWS = 65536;
constexpr int D     = 256;
constexpr int CODES = 1024;

constexpr float TAU_SCREEN = 2.5e-4f;
constexpr int   MAXPAIRS   = 7000000;

typedef __attribute__((ext_vector_type(8))) short short8;   // 8 bf16 = 4 VGPR
typedef __attribute__((ext_vector_type(4))) float f32x4;

// global -> LDS async 16B/lane: per-lane global src, wave-uniform LDS base,
// HW writes lane l -> base + l*16 (m97/m104 semantics).
__device__ __forceinline__ void gl2lds16(const unsigned short* g, unsigned short* l) {
    __builtin_amdgcn_global_load_lds(
        (const __attribute__((address_space(1))) void*)g,
        (__attribute__((address_space(3))) void*)l, 16, 0, 0);
}

// ---------------- fp32 -> bf16 (RNE) ----------------
__device__ __forceinline__ unsigned short f2bf(float x) {
    union { __hip_bfloat16 h; unsigned short u; } c;
    c.h = __float2bfloat16(x);
    return c.u;
}

__device__ __forceinline__ void cvt8(const float* __restrict__ src,
                                     unsigned short* __restrict__ dst, int i) {
    const float4* s = (const float4*)src + (size_t)i * 2;
    float4 a = s[0], b = s[1];
    union { unsigned short u[8]; uint4 v; } p;
    p.u[0] = f2bf(a.x); p.u[1] = f2bf(a.y); p.u[2] = f2bf(a.z); p.u[3] = f2bf(a.w);
    p.u[4] = f2bf(b.x); p.u[5] = f2bf(b.y); p.u[6] = f2bf(b.z); p.u[7] = f2bf(b.w);
    *(uint4*)(dst + (size_t)i * 8) = p.v;
}

// ---------------- fused prep ----------------
// blocks [0,8192): z->bf16 | [8192,8320): w->bf16 | [8320,8324): rownorm |
// [8324,8580): packed init + counters. rownorm in EXACT numpy pairwise order.
__global__ __launch_bounds__(256) void vq_prep(const float* __restrict__ z,
                                               unsigned short* __restrict__ zbf,
                                               const float* __restrict__ w,
                                               unsigned short* __restrict__ wbf,
                                               float* __restrict__ Cn,
                                               int* __restrict__ cnt,
                                               int* __restrict__ pcnt,
                                               unsigned long long* __restrict__ packed) {
    const int b = blockIdx.x;
    const int t = threadIdx.x;
    if (b < 8192) {
        cvt8(z, zbf, b * 256 + t);
    } else if (b < 8320) {
        cvt8(w, wbf, (b - 8192) * 256 + t);
    } else if (b < 8324) {
        const int row = (b - 8320) * 256 + t;
        const float4* p = (const float4*)(w + (size_t)row * D);
        float res[2];
        #pragma unroll
        for (int h = 0; h < 2; ++h) {
            float r[8];
            #pragma unroll
            for (int j = 0; j < 8; ++j) r[j] = 0.f;
            #pragma unroll 4
            for (int mm = 0; mm < 16; ++mm) {
                const float4 v0 = p[h * 32 + mm * 2];
                const float4 v1 = p[h * 32 + mm * 2 + 1];
                r[0] = __fadd_rn(r[0], __fmul_rn(v0.x, v0.x));
                r[1] = __fadd_rn(r[1], __fmul_rn(v0.y, v0.y));
                r[2] = __fadd_rn(r[2], __fmul_rn(v0.z, v0.z));
                r[3] = __fadd_rn(r[3], __fmul_rn(v0.w, v0.w));
                r[4] = __fadd_rn(r[4], __fmul_rn(v1.x, v1.x));
                r[5] = __fadd_rn(r[5], __fmul_rn(v1.y, v1.y));
                r[6] = __fadd_rn(r[6], __fmul_rn(v1.z, v1.z));
                r[7] = __fadd_rn(r[7], __fmul_rn(v1.w, v1.w));
            }
            res[h] = __fadd_rn(__fadd_rn(__fadd_rn(r[0], r[1]), __fadd_rn(r[2], r[3])),
                               __fadd_rn(__fadd_rn(r[4], r[5]), __fadd_rn(r[6], r[7])));
        }
        Cn[row] = __fadd_rn(res[0], res[1]);
    } else {
        const int i = (b - 8324) * 256 + t;
        packed[i] = ~0ull;
        if (i == 0) { *cnt = 0; *pcnt = 0; }
    }
}

// ---------------- bf16 MFMA screen (counted-vmcnt pipeline) ----------------
// 128 rows x 1024 codes per block; 32 steps (nb-major, ks-minor), dbuf LDS.
// Staging: LINEAR LDS dest + pre-swizzled global source (verified R4/absmax 0).
// Per step each wave issues exactly 8 global_load_lds; vmcnt(8) retires all
// older loads (in-order retirement) while the new 8 stay in flight.
__global__ __launch_bounds__(256, 2) void vq_screen(const unsigned short* __restrict__ zbf,
                                                    const unsigned short* __restrict__ wbf,
                                                    const float* __restrict__ Cn,
                                                    int* __restrict__ idx_out,
                                                    int* __restrict__ flagged,
                                                    int* __restrict__ cnt,
                                                    float* __restrict__ m1_out) {
    __shared__ unsigned short zT[2][128 * 64];
    __shared__ unsigned short wT[2][128 * 64];
    __shared__ float Cs[1024];
    __shared__ float rm1s[2][128];
    __shared__ float rm2s[2][128];
    __shared__ int   ris[2][128];

    const int t    = threadIdx.x;
    const int wv   = t >> 6;          // wave 0..3
    const int l    = t & 63;
    const int wm   = wv >> 1;         // row half
    const int wn   = wv & 1;          // col half
    const int m    = l & 15;
    const int quad = l >> 4;
    const int row0 = blockIdx.x * 128;

    // staging geometry (verified)
    const int  srow8   = l >> 3;
    const int  schunk  = (l & 7) ^ srow8;
    const size_t laneoff = (size_t)srow8 * D + schunk * 8;
    const bool stz   = (wv < 2);
    const int  sbase = (wv & 1) * 64;

    for (int i = t; i < 1024; i += 256) Cs[i] = Cn[i];

    float m1[4][4], m2[4][4];
    int   bi[4][4];
    f32x4 acc[4][4];
    #pragma unroll
    for (int mi = 0; mi < 4; ++mi)
        #pragma unroll
        for (int r = 0; r < 4; ++r) {
            m1[mi][r] = FLT_MAX; m2[mi][r] = FLT_MAX; bi[mi][r] = 0;
            acc[mi][r] = (f32x4){0.f, 0.f, 0.f, 0.f};
        }

    #define STAGE(s_, buf_) do {                                                   \
        const int nb_ = (s_) >> 2, ks_ = (s_) & 3;                                 \
        unsigned short* ldsb_ = stz ? &zT[buf_][sbase * 64] : &wT[buf_][sbase * 64];\
        const unsigned short* gb_ = stz                                            \
            ? zbf + (size_t)(row0 + sbase) * D + ks_ * 64                          \
            : wbf + (size_t)(nb_ * 128 + sbase) * D + ks_ * 64;                    \
        _Pragma("unroll")                                                          \
        for (int i_ = 0; i_ < 8; ++i_)                                             \
            gl2lds16(gb_ + (size_t)i_ * 8 * D + laneoff, ldsb_ + i_ * 512);        \
    } while (0)

    STAGE(0, 0);

    for (int s = 0; s < 32; ++s) {
        const int cur = s & 1;
        if (s < 31) {
            STAGE(s + 1, cur ^ 1);
            asm volatile("s_waitcnt vmcnt(8) lgkmcnt(0)" ::: "memory");
        } else {
            asm volatile("s_waitcnt vmcnt(0) lgkmcnt(0)" ::: "memory");
        }
        asm volatile("s_barrier" ::: "memory");

        #pragma unroll
        for (int kk = 0; kk < 2; ++kk) {
            short8 a[4], b[4];
            const int ch = kk * 4 + quad;
            const int co = (ch ^ (m & 7)) * 8;
            #pragma unroll
            for (int mi = 0; mi < 4; ++mi)
                a[mi] = *(const short8*)&zT[cur][(wm * 64 + mi * 16 + m) * 64 + co];
            #pragma unroll
            for (int ni = 0; ni < 4; ++ni)
                b[ni] = *(const short8*)&wT[cur][(wn * 64 + ni * 16 + m) * 64 + co];
            #pragma unroll
            for (int mi = 0; mi < 4; ++mi)
                #pragma unroll
                for (int ni = 0; ni < 4; ++ni)
                    acc[mi][ni] = __builtin_amdgcn_mfma_f32_16x16x32_bf16(
                        a[mi], b[ni], acc[mi][ni], 0, 0, 0);
        }
        if ((s & 3) == 3) {                    // nb complete: min-update + reset acc
            const int nb = s >> 2;
            #pragma unroll
            for (int ni = 0; ni < 4; ++ni) {
                const int code = nb * 128 + wn * 64 + ni * 16 + m;
                const float c  = Cs[code];
                #pragma unroll
                for (int mi = 0; mi < 4; ++mi)
                    #pragma unroll
                    for (int r = 0; r < 4; ++r) {
                        const float v = fmaf(-2.0f, acc[mi][ni][r], c);
                        if (v < m1[mi][r]) { m2[mi][r] = m1[mi][r]; m1[mi][r] = v; bi[mi][r] = code; }
                        else if (v < m2[mi][r]) m2[mi][r] = v;
                        acc[mi][ni][r] = 0.f;
                    }
            }
        }
        asm volatile("s_barrier" ::: "memory");
    }
    #undef STAGE

    // reduce across the 16 col-lanes (xor 1,2,4,8 varies l&15 only).
    #pragma unroll
    for (int mi = 0; mi < 4; ++mi)
        #pragma unroll
        for (int r = 0; r < 4; ++r) {
            float a1 = m1[mi][r], a2 = m2[mi][r];
            int   ai = bi[mi][r];
            #pragma unroll
            for (int off = 1; off <= 8; off <<= 1) {
                float o1 = __shfl_xor(a1, off, 64);
                float o2 = __shfl_xor(a2, off, 64);
                int   oi = __shfl_xor(ai, off, 64);
                float n2 = fminf(a2, o2);
                if (o1 < a1) { n2 = fminf(n2, a1); a1 = o1; ai = oi; }
                else n2 = fminf(n2, o1);
                a2 = n2;
            }
            m1[mi][r] = a1; m2[mi][r] = a2; bi[mi][r] = ai;
        }

    if (m == 0) {
        #pragma unroll
        for (int mi = 0; mi < 4; ++mi)
            #pragma unroll
            for (int r = 0; r < 4; ++r) {
                const int rl = wm * 64 + mi * 16 + quad * 4 + r;
                rm1s[wn][rl] = m1[mi][r];
                rm2s[wn][rl] = m2[mi][r];
                ris[wn][rl]  = bi[mi][r];
            }
    }
    __syncthreads();
    if (t < 128) {
        float a1 = rm1s[0][t], a2 = rm2s[0][t];
        int   ai = ris[0][t];
        const float o1 = rm1s[1][t], o2 = rm2s[1][t];
        const int   oi = ris[1][t];
        float n2 = fminf(a2, o2);
        if (o1 < a1) { n2 = fminf(n2, a1); a1 = o1; ai = oi; }
        else n2 = fminf(n2, o1);
        a2 = n2;
        const int row = row0 + t;
        idx_out[row] = ai;
        m1_out[row]  = a1;
        if (a2 - a1 < TAU_SCREEN) {
            int p = atomicAdd(cnt, 1);
            flagged[p] = row;
        }
    }
}

// ---------------- candidate emit (tile x nb jobs + counted-vmcnt) ----------------
// Job = (128 gathered flagged rows) x (one 128-code nb); ~296 jobs on 512 blocks.
// 4-step pipeline (ks 0..3); acc accumulates across ks; emission after the loop
// (no VMEM inside the pipeline). Bitwise-identical MFMA order to vq_screen.
__global__ __launch_bounds__(256, 2) void vq_cand(const unsigned short* __restrict__ zbf,
                                                  const unsigned short* __restrict__ wbf,
                                                  const float* __restrict__ Cn,
                                                  const float* __restrict__ m1g,
                                                  const int* __restrict__ flagged,
                                                  const int* __restrict__ cnt,
                                                  uint32_t* __restrict__ pairs,
                                                  int* __restrict__ pcnt) {
    __shared__ unsigned short zT[2][128 * 64];
    __shared__ unsigned short wT[2][128 * 64];
    __shared__ int rows_s[128];

    const int t    = threadIdx.x;
    const int wv   = t >> 6;
    const int l    = t & 63;
    const int wm   = wv >> 1;
    const int wn   = wv & 1;
    const int m    = l & 15;
    const int quad = l >> 4;

    const int  srow8   = l >> 3;
    const int  schunk  = (l & 7) ^ srow8;
    const size_t laneoff_w = (size_t)srow8 * D + schunk * 8;
    const bool stz   = (wv < 2);
    const int  sbase = (wv & 1) * 64;

    const int n     = *cnt;
    const int njobs = ((n + 127) >> 7) << 3;

    for (int job = blockIdx.x; job < njobs; job += gridDim.x) {
        const int tile = job >> 3;
        const int nb   = job & 7;
        __syncthreads();                     // LDS reuse guard (implicit full drain)
        if (t < 128) {
            const int fi = tile * 128 + t;
            rows_s[t] = (fi < n) ? flagged[fi] : -1;
        }
        __syncthreads();

        int zrow[8];
        #pragma unroll
        for (int i = 0; i < 8; ++i) {
            const int rr = rows_s[sbase + i * 8 + srow8];
            zrow[i] = rr < 0 ? 0 : rr;
        }
        int   rowid[4][4];
        float thr[4][4];
        #pragma unroll
        for (int mi = 0; mi < 4; ++mi)
            #pragma unroll
            for (int r = 0; r < 4; ++r) {
                const int rl = wm * 64 + mi * 16 + quad * 4 + r;
                const int ri = rows_s[rl];
                rowid[mi][r] = ri;
                thr[mi][r]   = (ri >= 0) ? m1g[ri] + TAU_SCREEN : -FLT_MAX;
            }

        f32x4 acc[4][4];
        #pragma unroll
        for (int mi = 0; mi < 4; ++mi)
            #pragma unroll
            for (int ni = 0; ni < 4; ++ni) acc[mi][ni] = (f32x4){0.f, 0.f, 0.f, 0.f};

        #define STAGEC(ks_, buf_) do {                                                \
            if (stz) {                                                                \
                unsigned short* ldsb_ = &zT[buf_][sbase * 64];                        \
                _Pragma("unroll")                                                     \
                for (int i_ = 0; i_ < 8; ++i_)                                        \
                    gl2lds16(zbf + (size_t)zrow[i_] * D + (ks_) * 64 + schunk * 8,    \
                             ldsb_ + i_ * 512);                                       \
            } else {                                                                  \
                unsigned short* ldsb_ = &wT[buf_][sbase * 64];                        \
                const unsigned short* gb_ =                                           \
                    wbf + (size_t)(nb * 128 + sbase) * D + (ks_) * 64;                \
                _Pragma("unroll")                                                     \
                for (int i_ = 0; i_ < 8; ++i_)                                        \
                    gl2lds16(gb_ + (size_t)i_ * 8 * D + laneoff_w, ldsb_ + i_ * 512); \
            }                                                                         \
        } while (0)

        STAGEC(0, 0);
        for (int ks = 0; ks < 4; ++ks) {
            const int cur = ks & 1;
            if (ks < 3) {
                STAGEC(ks + 1, cur ^ 1);
                asm volatile("s_waitcnt vmcnt(8) lgkmcnt(0)" ::: "memory");
            } else {
                asm volatile("s_waitcnt vmcnt(0) lgkmcnt(0)" ::: "memory");
            }
            asm volatile("s_barrier" ::: "memory");
            #pragma unroll
            for (int kk = 0; kk < 2; ++kk) {
                short8 a[4], b[4];
                const int ch = kk * 4 + quad;
                const int co = (ch ^ (m & 7)) * 8;
                #pragma unroll
                for (int mi = 0; mi < 4; ++mi)
                    a[mi] = *(const short8*)&zT[cur][(wm * 64 + mi * 16 + m) * 64 + co];
                #pragma unroll
                for (int ni = 0; ni < 4; ++ni)
                    b[ni] = *(const short8*)&wT[cur][(wn * 64 + ni * 16 + m) * 64 + co];
                #pragma unroll
                for (int mi = 0; mi < 4; ++mi)
                    #pragma unroll
                    for (int ni = 0; ni < 4; ++ni)
                        acc[mi][ni] = __builtin_amdgcn_mfma_f32_16x16x32_bf16(
                            a[mi], b[ni], acc[mi][ni], 0, 0, 0);
            }
            asm volatile("s_barrier" ::: "memory");
        }
        #undef STAGEC

        // emission for this nb
        #pragma unroll
        for (int ni = 0; ni < 4; ++ni) {
            const int code = nb * 128 + wn * 64 + ni * 16 + m;
            const float c  = Cn[code];
            #pragma unroll
            for (int mi = 0; mi < 4; ++mi)
                #pragma unroll
                for (int r = 0; r < 4; ++r) {
                    const float v = fmaf(-2.0f, acc[mi][ni][r], c);
                    if (v < thr[mi][r]) {
                        const int p = atomicAdd(pcnt, 1);
                        if (p < MAXPAIRS)
                            pairs[p] = ((uint32_t)rowid[mi][r] << 16) | (uint32_t)code;
                    }
                }
        }
    }
}

// ---------------- exact eval: one lane per (row,code) pair ----------------
__global__ __launch_bounds__(256) void vq_exact(const float* __restrict__ z,
                                                const float* __restrict__ w,
                                                const float* __restrict__ Cn,
                                                const uint32_t* __restrict__ pairs,
                                                const int* __restrict__ pcnt,
                                                unsigned long long* __restrict__ packed) {
    const int np0 = *pcnt;
    const int np  = np0 < MAXPAIRS ? np0 : MAXPAIRS;
    for (int g = blockIdx.x * 256 + threadIdx.x; g < np; g += gridDim.x * 256) {
        const uint32_t pr = pairs[g];
        const int row  = (int)(pr >> 16);
        const int code = (int)(pr & 0xffffu);
        const float4* zp = (const float4*)(z + (size_t)row * D);
        const float4* wp = (const float4*)(w + (size_t)code * D);
        float B = 0.f;
        float res[2];
        #pragma unroll
        for (int b = 0; b < 2; ++b) {
            float r[8];
            #pragma unroll
            for (int j = 0; j < 8; ++j) r[j] = 0.f;
            #pragma unroll 4
            for (int mm = 0; mm < 16; ++mm) {
                const float4 z0 = zp[b * 32 + mm * 2];
                const float4 z1 = zp[b * 32 + mm * 2 + 1];
                const float4 w0 = wp[b * 32 + mm * 2];
                const float4 w1 = wp[b * 32 + mm * 2 + 1];
                r[0] = __fadd_rn(r[0], __fmul_rn(z0.x, z0.x));
                r[1] = __fadd_rn(r[1], __fmul_rn(z0.y, z0.y));
                r[2] = __fadd_rn(r[2], __fmul_rn(z0.z, z0.z));
                r[3] = __fadd_rn(r[3], __fmul_rn(z0.w, z0.w));
                r[4] = __fadd_rn(r[4], __fmul_rn(z1.x, z1.x));
                r[5] = __fadd_rn(r[5], __fmul_rn(z1.y, z1.y));
                r[6] = __fadd_rn(r[6], __fmul_rn(z1.z, z1.z));
                r[7] = __fadd_rn(r[7], __fmul_rn(z1.w, z1.w));
                B = fmaf(z0.x, w0.x, B); B = fmaf(z0.y, w0.y, B);
                B = fmaf(z0.z, w0.z, B); B = fmaf(z0.w, w0.w, B);
                B = fmaf(z1.x, w1.x, B); B = fmaf(z1.y, w1.y, B);
                B = fmaf(z1.z, w1.z, B); B = fmaf(z1.w, w1.w, B);
            }
            res[b] = __fadd_rn(__fadd_rn(__fadd_rn(r[0], r[1]), __fadd_rn(r[2], r[3])),
                               __fadd_rn(__fadd_rn(r[4], r[5]), __fadd_rn(r[6], r[7])));
        }
        const float A = __fadd_rn(res[0], res[1]);
        const float d = __fadd_rn(__fsub_rn(A, __fmul_rn(2.0f, B)), Cn[code]);
        const uint32_t bits = __float_as_uint(d);
        const uint32_t ord  = (bits & 0x80000000u) ? ~bits : (bits | 0x80000000u);
        const unsigned long long key =
            ((unsigned long long)ord << 32) | (unsigned long long)(uint32_t)code;
        atomicMin(&packed[row], key);
    }
}

// ---------------- unpack refined indices (separate kernel: packed must be
// fully consumed before vq_gather overwrites its d_out region) ----------------
__global__ __launch_bounds__(256) void vq_unpack(const int* __restrict__ flagged,
                                                 const int* __restrict__ cnt,
                                                 const unsigned long long* __restrict__ packed,
                                                 int* __restrict__ idx) {
    const int n = *cnt;
    for (int g = blockIdx.x * 256 + threadIdx.x; g < n; g += gridDim.x * 256) {
        const int row = flagged[g];
        idx[row] = (int)(packed[row] & 0xffffffffull);
    }
}

// ---------------- gather ----------------
__global__ __launch_bounds__(256) void vq_gather(const float* __restrict__ w,
                                                 const int* __restrict__ idx,
                                                 float* __restrict__ outq,
                                                 float* __restrict__ outi) {
    const int t    = threadIdx.x;
    const int lane = t & 63;
    const int sub  = t >> 6;
    const int row0 = blockIdx.x * 128;
    #pragma unroll 4
    for (int it = 0; it < 32; ++it) {
        const int row = row0 + it * 4 + sub;
        const int j   = idx[row];
        ((float4*)outq)[(size_t)row * 64 + lane] = ((const float4*)w)[(size_t)j * 64 + lane];
        if (lane == 0) outi[row] = (float)j;
    }
}

extern "C" void kernel_launch(void* const* d_in, const int* in_sizes, int n_in,
                              void* d_out, int out_size, void* d_ws, size_t ws_size,
                              hipStream_t stream) {
    const float* z = (const float*)d_in[0];
    const float* w = (const float*)d_in[1];
    float* outq = (float*)d_out;
    float* outi = outq + (size_t)NROWS * D;

    // scratch inside d_out (all dead before vq_gather):
    //   zbf   [0, 32MB)        bf16 z
    //   wbf   [32MB, 32.5MB)   bf16 w
    //   Cn    [32.5MB, +4KB)   |w|^2
    //   m1g   [35MB, +256KB)   per-row screen min1
    //   packed[35.5MB, +512KB) per-row (ordered-d, code) u64
    //   pairs [36MB, ...)      candidate (row<<16|code) u32, cap MAXPAIRS
    unsigned short*     zbf    = (unsigned short*)d_out;
    unsigned short*     wbf    = (unsigned short*)((char*)d_out + 33554432);
    float*              Cn     = (float*)((char*)d_out + 34078720);
    float*              m1g    = (float*)((char*)d_out + 36700160);
    unsigned long long* packed = (unsigned long long*)((char*)d_out + 37224448);
    uint32_t*           pairs  = (uint32_t*)((char*)d_out + 37748736);

    char* ws      = (char*)d_ws;
    int*  idx     = (int*)ws;
    int*  flagged = (int*)(ws + 262144);
    int*  cnt     = (int*)(ws + 524288);
    int*  pcnt    = (int*)(ws + 524292);

    vq_prep<<<8580, 256, 0, stream>>>(z, zbf, w, wbf, Cn, cnt, pcnt, packed);
    vq_screen<<<NROWS / 128, 256, 0, stream>>>(zbf, wbf, Cn, idx, flagged, cnt, m1g);
    vq_cand<<<512, 256, 0, stream>>>(zbf, wbf, Cn, m1g, flagged, cnt, pairs, pcnt);
    vq_exact<<<256, 256, 0, stream>>>(z, w, Cn, pairs, pcnt, packed);
    vq_unpack<<<64, 256, 0, stream>>>(flagged, cnt, packed, idx);
    vq_gather<<<NROWS / 128, 256, 0, stream>>>(w, idx, outq, outi);
}

// Round 7
// 233.142 us; speedup vs baseline: 2.5731x; 1.2550x over previous
//
#include <hip/hip_runtime.h>
#include <hip/hip_bf16.h>
#include <stdint.h>
#include <float.h>

// VQ quantize: z[65536,256] f32, weight[1024,256] f32.
// ref (numpy fp32): d = fl32(fl32(A - 2*B) + C); idx = argmax(-d) (first-index ties).
// Outputs (float32, concat): quantized [65536*256], indices [65536].
//
// Pipeline:
//   1) vq_prep: fused {init counters/packed, z->bf16, w->bf16, Cn=|w|^2 exact}
//   2) vq_screen: bf16 MFMA 16x16x32 GEMM (scores = C - 2*z.wT), per-row
//      (min1,min2,idx); rows with margin < TAU flagged (n ~ 4700, 7%); m1 stored.
//      Counted-vmcnt pipeline (proven R6: screen dropped below cand).
//   3) vq_cand: (tile x nb) jobs, counted-vmcnt 4-step pipeline; emits
//      (row,code) with score < m1+TAU. R9: hierarchical emission -- ~74K pairs
//      were issued as same-address global atomicAdd(pcnt,1), serializing at one
//      L2 slot (~77us invariant across R3/R4/R6 schedules). Now: LDS list
//      (aliased over dead tiles; capacity 16384 = full 128x128 tile, cannot
//      overflow) + LDS counter + ONE global atomicAdd per block + coalesced copy.
//   4) vq_exact: one lane per pair; bit-exact numpy-fp32 chain (pairwise A,
//      sequential-k fma B -- proven absmax=0); atomicMin packed (ordered-d, code)
//      -- order-independent, so emission reordering is safe.
//   5) vq_unpack: separate kernel (R5 lesson: packed lives in d_out and must be
//      consumed before vq_gather overwrites it).
//   6) vq_gather.

constexpr int NROWS = 65536;
constexpr int D     = 256;
constexpr int CODES = 1024;

constexpr float TAU_SCREEN = 2.5e-4f;
constexpr int   MAXPAIRS   = 7000000;

typedef __attribute__((ext_vector_type(8))) short short8;   // 8 bf16 = 4 VGPR
typedef __attribute__((ext_vector_type(4))) float f32x4;

// global -> LDS async 16B/lane: per-lane global src, wave-uniform LDS base,
// HW writes lane l -> base + l*16 (m97/m104 semantics).
__device__ __forceinline__ void gl2lds16(const unsigned short* g, unsigned short* l) {
    __builtin_amdgcn_global_load_lds(
        (const __attribute__((address_space(1))) void*)g,
        (__attribute__((address_space(3))) void*)l, 16, 0, 0);
}

// ---------------- fp32 -> bf16 (RNE) ----------------
__device__ __forceinline__ unsigned short f2bf(float x) {
    union { __hip_bfloat16 h; unsigned short u; } c;
    c.h = __float2bfloat16(x);
    return c.u;
}

__device__ __forceinline__ void cvt8(const float* __restrict__ src,
                                     unsigned short* __restrict__ dst, int i) {
    const float4* s = (const float4*)src + (size_t)i * 2;
    float4 a = s[0], b = s[1];
    union { unsigned short u[8]; uint4 v; } p;
    p.u[0] = f2bf(a.x); p.u[1] = f2bf(a.y); p.u[2] = f2bf(a.z); p.u[3] = f2bf(a.w);
    p.u[4] = f2bf(b.x); p.u[5] = f2bf(b.y); p.u[6] = f2bf(b.z); p.u[7] = f2bf(b.w);
    *(uint4*)(dst + (size_t)i * 8) = p.v;
}

// ---------------- fused prep ----------------
// blocks [0,8192): z->bf16 | [8192,8320): w->bf16 | [8320,8324): rownorm |
// [8324,8580): packed init + counters. rownorm in EXACT numpy pairwise order.
__global__ __launch_bounds__(256) void vq_prep(const float* __restrict__ z,
                                               unsigned short* __restrict__ zbf,
                                               const float* __restrict__ w,
                                               unsigned short* __restrict__ wbf,
                                               float* __restrict__ Cn,
                                               int* __restrict__ cnt,
                                               int* __restrict__ pcnt,
                                               unsigned long long* __restrict__ packed) {
    const int b = blockIdx.x;
    const int t = threadIdx.x;
    if (b < 8192) {
        cvt8(z, zbf, b * 256 + t);
    } else if (b < 8320) {
        cvt8(w, wbf, (b - 8192) * 256 + t);
    } else if (b < 8324) {
        const int row = (b - 8320) * 256 + t;
        const float4* p = (const float4*)(w + (size_t)row * D);
        float res[2];
        #pragma unroll
        for (int h = 0; h < 2; ++h) {
            float r[8];
            #pragma unroll
            for (int j = 0; j < 8; ++j) r[j] = 0.f;
            #pragma unroll 4
            for (int mm = 0; mm < 16; ++mm) {
                const float4 v0 = p[h * 32 + mm * 2];
                const float4 v1 = p[h * 32 + mm * 2 + 1];
                r[0] = __fadd_rn(r[0], __fmul_rn(v0.x, v0.x));
                r[1] = __fadd_rn(r[1], __fmul_rn(v0.y, v0.y));
                r[2] = __fadd_rn(r[2], __fmul_rn(v0.z, v0.z));
                r[3] = __fadd_rn(r[3], __fmul_rn(v0.w, v0.w));
                r[4] = __fadd_rn(r[4], __fmul_rn(v1.x, v1.x));
                r[5] = __fadd_rn(r[5], __fmul_rn(v1.y, v1.y));
                r[6] = __fadd_rn(r[6], __fmul_rn(v1.z, v1.z));
                r[7] = __fadd_rn(r[7], __fmul_rn(v1.w, v1.w));
            }
            res[h] = __fadd_rn(__fadd_rn(__fadd_rn(r[0], r[1]), __fadd_rn(r[2], r[3])),
                               __fadd_rn(__fadd_rn(r[4], r[5]), __fadd_rn(r[6], r[7])));
        }
        Cn[row] = __fadd_rn(res[0], res[1]);
    } else {
        const int i = (b - 8324) * 256 + t;
        packed[i] = ~0ull;
        if (i == 0) { *cnt = 0; *pcnt = 0; }
    }
}

// ---------------- bf16 MFMA screen (counted-vmcnt pipeline) ----------------
// 128 rows x 1024 codes per block; 32 steps (nb-major, ks-minor), dbuf LDS.
// Staging: LINEAR LDS dest + pre-swizzled global source (verified R4/absmax 0).
// Per step each wave issues exactly 8 global_load_lds; vmcnt(8) retires all
// older loads (in-order retirement) while the new 8 stay in flight.
__global__ __launch_bounds__(256, 2) void vq_screen(const unsigned short* __restrict__ zbf,
                                                    const unsigned short* __restrict__ wbf,
                                                    const float* __restrict__ Cn,
                                                    int* __restrict__ idx_out,
                                                    int* __restrict__ flagged,
                                                    int* __restrict__ cnt,
                                                    float* __restrict__ m1_out) {
    __shared__ unsigned short zT[2][128 * 64];
    __shared__ unsigned short wT[2][128 * 64];
    __shared__ float Cs[1024];
    __shared__ float rm1s[2][128];
    __shared__ float rm2s[2][128];
    __shared__ int   ris[2][128];

    const int t    = threadIdx.x;
    const int wv   = t >> 6;          // wave 0..3
    const int l    = t & 63;
    const int wm   = wv >> 1;         // row half
    const int wn   = wv & 1;          // col half
    const int m    = l & 15;
    const int quad = l >> 4;
    const int row0 = blockIdx.x * 128;

    // staging geometry (verified)
    const int  srow8   = l >> 3;
    const int  schunk  = (l & 7) ^ srow8;
    const size_t laneoff = (size_t)srow8 * D + schunk * 8;
    const bool stz   = (wv < 2);
    const int  sbase = (wv & 1) * 64;

    for (int i = t; i < 1024; i += 256) Cs[i] = Cn[i];

    float m1[4][4], m2[4][4];
    int   bi[4][4];
    f32x4 acc[4][4];
    #pragma unroll
    for (int mi = 0; mi < 4; ++mi)
        #pragma unroll
        for (int r = 0; r < 4; ++r) {
            m1[mi][r] = FLT_MAX; m2[mi][r] = FLT_MAX; bi[mi][r] = 0;
            acc[mi][r] = (f32x4){0.f, 0.f, 0.f, 0.f};
        }

    #define STAGE(s_, buf_) do {                                                   \
        const int nb_ = (s_) >> 2, ks_ = (s_) & 3;                                 \
        unsigned short* ldsb_ = stz ? &zT[buf_][sbase * 64] : &wT[buf_][sbase * 64];\
        const unsigned short* gb_ = stz                                            \
            ? zbf + (size_t)(row0 + sbase) * D + ks_ * 64                          \
            : wbf + (size_t)(nb_ * 128 + sbase) * D + ks_ * 64;                    \
        _Pragma("unroll")                                                          \
        for (int i_ = 0; i_ < 8; ++i_)                                             \
            gl2lds16(gb_ + (size_t)i_ * 8 * D + laneoff, ldsb_ + i_ * 512);        \
    } while (0)

    STAGE(0, 0);

    for (int s = 0; s < 32; ++s) {
        const int cur = s & 1;
        if (s < 31) {
            STAGE(s + 1, cur ^ 1);
            asm volatile("s_waitcnt vmcnt(8) lgkmcnt(0)" ::: "memory");
        } else {
            asm volatile("s_waitcnt vmcnt(0) lgkmcnt(0)" ::: "memory");
        }
        asm volatile("s_barrier" ::: "memory");

        #pragma unroll
        for (int kk = 0; kk < 2; ++kk) {
            short8 a[4], b[4];
            const int ch = kk * 4 + quad;
            const int co = (ch ^ (m & 7)) * 8;
            #pragma unroll
            for (int mi = 0; mi < 4; ++mi)
                a[mi] = *(const short8*)&zT[cur][(wm * 64 + mi * 16 + m) * 64 + co];
            #pragma unroll
            for (int ni = 0; ni < 4; ++ni)
                b[ni] = *(const short8*)&wT[cur][(wn * 64 + ni * 16 + m) * 64 + co];
            #pragma unroll
            for (int mi = 0; mi < 4; ++mi)
                #pragma unroll
                for (int ni = 0; ni < 4; ++ni)
                    acc[mi][ni] = __builtin_amdgcn_mfma_f32_16x16x32_bf16(
                        a[mi], b[ni], acc[mi][ni], 0, 0, 0);
        }
        if ((s & 3) == 3) {                    // nb complete: min-update + reset acc
            const int nb = s >> 2;
            #pragma unroll
            for (int ni = 0; ni < 4; ++ni) {
                const int code = nb * 128 + wn * 64 + ni * 16 + m;
                const float c  = Cs[code];
                #pragma unroll
                for (int mi = 0; mi < 4; ++mi)
                    #pragma unroll
                    for (int r = 0; r < 4; ++r) {
                        const float v = fmaf(-2.0f, acc[mi][ni][r], c);
                        if (v < m1[mi][r]) { m2[mi][r] = m1[mi][r]; m1[mi][r] = v; bi[mi][r] = code; }
                        else if (v < m2[mi][r]) m2[mi][r] = v;
                        acc[mi][ni][r] = 0.f;
                    }
            }
        }
        asm volatile("s_barrier" ::: "memory");
    }
    #undef STAGE

    // reduce across the 16 col-lanes (xor 1,2,4,8 varies l&15 only).
    #pragma unroll
    for (int mi = 0; mi < 4; ++mi)
        #pragma unroll
        for (int r = 0; r < 4; ++r) {
            float a1 = m1[mi][r], a2 = m2[mi][r];
            int   ai = bi[mi][r];
            #pragma unroll
            for (int off = 1; off <= 8; off <<= 1) {
                float o1 = __shfl_xor(a1, off, 64);
                float o2 = __shfl_xor(a2, off, 64);
                int   oi = __shfl_xor(ai, off, 64);
                float n2 = fminf(a2, o2);
                if (o1 < a1) { n2 = fminf(n2, a1); a1 = o1; ai = oi; }
                else n2 = fminf(n2, o1);
                a2 = n2;
            }
            m1[mi][r] = a1; m2[mi][r] = a2; bi[mi][r] = ai;
        }

    if (m == 0) {
        #pragma unroll
        for (int mi = 0; mi < 4; ++mi)
            #pragma unroll
            for (int r = 0; r < 4; ++r) {
                const int rl = wm * 64 + mi * 16 + quad * 4 + r;
                rm1s[wn][rl] = m1[mi][r];
                rm2s[wn][rl] = m2[mi][r];
                ris[wn][rl]  = bi[mi][r];
            }
    }
    __syncthreads();
    if (t < 128) {
        float a1 = rm1s[0][t], a2 = rm2s[0][t];
        int   ai = ris[0][t];
        const float o1 = rm1s[1][t], o2 = rm2s[1][t];
        const int   oi = ris[1][t];
        float n2 = fminf(a2, o2);
        if (o1 < a1) { n2 = fminf(n2, a1); a1 = o1; ai = oi; }
        else n2 = fminf(n2, o1);
        a2 = n2;
        const int row = row0 + t;
        idx_out[row] = ai;
        m1_out[row]  = a1;
        if (a2 - a1 < TAU_SCREEN) {
            int p = atomicAdd(cnt, 1);
            flagged[p] = row;
        }
    }
}

// ---------------- candidate emit (tile x nb jobs, counted-vmcnt, LDS-agg emission) ----
// Job = (128 gathered flagged rows) x (one 128-code nb); ~296 jobs on 512 blocks.
// 4-step pipeline; emission after the loop into an LDS list aliased over the
// DEAD tile buffers (capacity 16384 = full 128x128 tile => cannot overflow),
// then ONE global atomicAdd per block + coalesced copy. (R6: ~74K same-address
// global atomics serialized at one L2 slot = the 77us invariant.)
__global__ __launch_bounds__(256, 2) void vq_cand(const unsigned short* __restrict__ zbf,
                                                  const unsigned short* __restrict__ wbf,
                                                  const float* __restrict__ Cn,
                                                  const float* __restrict__ m1g,
                                                  const int* __restrict__ flagged,
                                                  const int* __restrict__ cnt,
                                                  uint32_t* __restrict__ pairs,
                                                  int* __restrict__ pcnt) {
    __shared__ union SM {
        struct { unsigned short zT[2][128 * 64]; unsigned short wT[2][128 * 64]; } tl;
        uint32_t list[16384];                  // aliases tiles; used only post-pipeline
    } sm;
    __shared__ int rows_s[128];
    __shared__ int lcnt;
    __shared__ int gbase;

    const int t    = threadIdx.x;
    const int wv   = t >> 6;
    const int l    = t & 63;
    const int wm   = wv >> 1;
    const int wn   = wv & 1;
    const int m    = l & 15;
    const int quad = l >> 4;

    const int  srow8   = l >> 3;
    const int  schunk  = (l & 7) ^ srow8;
    const size_t laneoff_w = (size_t)srow8 * D + schunk * 8;
    const bool stz   = (wv < 2);
    const int  sbase = (wv & 1) * 64;

    const int n     = *cnt;
    const int njobs = ((n + 127) >> 7) << 3;

    for (int job = blockIdx.x; job < njobs; job += gridDim.x) {
        const int tile = job >> 3;
        const int nb   = job & 7;
        __syncthreads();                     // LDS reuse guard (implicit full drain)
        if (t < 128) {
            const int fi = tile * 128 + t;
            rows_s[t] = (fi < n) ? flagged[fi] : -1;
        }
        if (t == 0) lcnt = 0;
        __syncthreads();

        int zrow[8];
        #pragma unroll
        for (int i = 0; i < 8; ++i) {
            const int rr = rows_s[sbase + i * 8 + srow8];
            zrow[i] = rr < 0 ? 0 : rr;
        }
        int   rowid[4][4];
        float thr[4][4];
        #pragma unroll
        for (int mi = 0; mi < 4; ++mi)
            #pragma unroll
            for (int r = 0; r < 4; ++r) {
                const int rl = wm * 64 + mi * 16 + quad * 4 + r;
                const int ri = rows_s[rl];
                rowid[mi][r] = ri;
                thr[mi][r]   = (ri >= 0) ? m1g[ri] + TAU_SCREEN : -FLT_MAX;
            }

        f32x4 acc[4][4];
        #pragma unroll
        for (int mi = 0; mi < 4; ++mi)
            #pragma unroll
            for (int ni = 0; ni < 4; ++ni) acc[mi][ni] = (f32x4){0.f, 0.f, 0.f, 0.f};

        #define STAGEC(ks_, buf_) do {                                                \
            if (stz) {                                                                \
                unsigned short* ldsb_ = &sm.tl.zT[buf_][sbase * 64];                  \
                _Pragma("unroll")                                                     \
                for (int i_ = 0; i_ < 8; ++i_)                                        \
                    gl2lds16(zbf + (size_t)zrow[i_] * D + (ks_) * 64 + schunk * 8,    \
                             ldsb_ + i_ * 512);                                       \
            } else {                                                                  \
                unsigned short* ldsb_ = &sm.tl.wT[buf_][sbase * 64];                  \
                const unsigned short* gb_ =                                           \
                    wbf + (size_t)(nb * 128 + sbase) * D + (ks_) * 64;                \
                _Pragma("unroll")                                                     \
                for (int i_ = 0; i_ < 8; ++i_)                                        \
                    gl2lds16(gb_ + (size_t)i_ * 8 * D + laneoff_w, ldsb_ + i_ * 512); \
            }                                                                         \
        } while (0)

        STAGEC(0, 0);
        for (int ks = 0; ks < 4; ++ks) {
            const int cur = ks & 1;
            if (ks < 3) {
                STAGEC(ks + 1, cur ^ 1);
                asm volatile("s_waitcnt vmcnt(8) lgkmcnt(0)" ::: "memory");
            } else {
                asm volatile("s_waitcnt vmcnt(0) lgkmcnt(0)" ::: "memory");
            }
            asm volatile("s_barrier" ::: "memory");
            #pragma unroll
            for (int kk = 0; kk < 2; ++kk) {
                short8 a[4], b[4];
                const int ch = kk * 4 + quad;
                const int co = (ch ^ (m & 7)) * 8;
                #pragma unroll
                for (int mi = 0; mi < 4; ++mi)
                    a[mi] = *(const short8*)&sm.tl.zT[cur][(wm * 64 + mi * 16 + m) * 64 + co];
                #pragma unroll
                for (int ni = 0; ni < 4; ++ni)
                    b[ni] = *(const short8*)&sm.tl.wT[cur][(wn * 64 + ni * 16 + m) * 64 + co];
                #pragma unroll
                for (int mi = 0; mi < 4; ++mi)
                    #pragma unroll
                    for (int ni = 0; ni < 4; ++ni)
                        acc[mi][ni] = __builtin_amdgcn_mfma_f32_16x16x32_bf16(
                            a[mi], b[ni], acc[mi][ni], 0, 0, 0);
            }
            asm volatile("s_barrier" ::: "memory");
        }
        #undef STAGEC
        // tiles are dead from here (all waves passed the final barrier);
        // sm.list may now alias them.

        // emission for this nb: LDS-aggregated
        #pragma unroll
        for (int ni = 0; ni < 4; ++ni) {
            const int code = nb * 128 + wn * 64 + ni * 16 + m;
            const float c  = Cn[code];
            #pragma unroll
            for (int mi = 0; mi < 4; ++mi)
                #pragma unroll
                for (int r = 0; r < 4; ++r) {
                    const float v = fmaf(-2.0f, acc[mi][ni][r], c);
                    if (v < thr[mi][r]) {
                        const int p = atomicAdd(&lcnt, 1);   // LDS atomic
                        sm.list[p] = ((uint32_t)rowid[mi][r] << 16) | (uint32_t)code;
                    }
                }
        }
        __syncthreads();
        if (t == 0) gbase = atomicAdd(pcnt, lcnt);           // ONE global atomic
        __syncthreads();
        const int nc = lcnt;
        const int gb = gbase;
        for (int i = t; i < nc; i += 256) {
            const int p = gb + i;
            if (p < MAXPAIRS) pairs[p] = sm.list[i];
        }
    }
}

// ---------------- exact eval: one lane per (row,code) pair ----------------
__global__ __launch_bounds__(256) void vq_exact(const float* __restrict__ z,
                                                const float* __restrict__ w,
                                                const float* __restrict__ Cn,
                                                const uint32_t* __restrict__ pairs,
                                                const int* __restrict__ pcnt,
                                                unsigned long long* __restrict__ packed) {
    const int np0 = *pcnt;
    const int np  = np0 < MAXPAIRS ? np0 : MAXPAIRS;
    for (int g = blockIdx.x * 256 + threadIdx.x; g < np; g += gridDim.x * 256) {
        const uint32_t pr = pairs[g];
        const int row  = (int)(pr >> 16);
        const int code = (int)(pr & 0xffffu);
        const float4* zp = (const float4*)(z + (size_t)row * D);
        const float4* wp = (const float4*)(w + (size_t)code * D);
        float B = 0.f;
        float res[2];
        #pragma unroll
        for (int b = 0; b < 2; ++b) {
            float r[8];
            #pragma unroll
            for (int j = 0; j < 8; ++j) r[j] = 0.f;
            #pragma unroll 4
            for (int mm = 0; mm < 16; ++mm) {
                const float4 z0 = zp[b * 32 + mm * 2];
                const float4 z1 = zp[b * 32 + mm * 2 + 1];
                const float4 w0 = wp[b * 32 + mm * 2];
                const float4 w1 = wp[b * 32 + mm * 2 + 1];
                r[0] = __fadd_rn(r[0], __fmul_rn(z0.x, z0.x));
                r[1] = __fadd_rn(r[1], __fmul_rn(z0.y, z0.y));
                r[2] = __fadd_rn(r[2], __fmul_rn(z0.z, z0.z));
                r[3] = __fadd_rn(r[3], __fmul_rn(z0.w, z0.w));
                r[4] = __fadd_rn(r[4], __fmul_rn(z1.x, z1.x));
                r[5] = __fadd_rn(r[5], __fmul_rn(z1.y, z1.y));
                r[6] = __fadd_rn(r[6], __fmul_rn(z1.z, z1.z));
                r[7] = __fadd_rn(r[7], __fmul_rn(z1.w, z1.w));
                B = fmaf(z0.x, w0.x, B); B = fmaf(z0.y, w0.y, B);
                B = fmaf(z0.z, w0.z, B); B = fmaf(z0.w, w0.w, B);
                B = fmaf(z1.x, w1.x, B); B = fmaf(z1.y, w1.y, B);
                B = fmaf(z1.z, w1.z, B); B = fmaf(z1.w, w1.w, B);
            }
            res[b] = __fadd_rn(__fadd_rn(__fadd_rn(r[0], r[1]), __fadd_rn(r[2], r[3])),
                               __fadd_rn(__fadd_rn(r[4], r[5]), __fadd_rn(r[6], r[7])));
        }
        const float A = __fadd_rn(res[0], res[1]);
        const float d = __fadd_rn(__fsub_rn(A, __fmul_rn(2.0f, B)), Cn[code]);
        const uint32_t bits = __float_as_uint(d);
        const uint32_t ord  = (bits & 0x80000000u) ? ~bits : (bits | 0x80000000u);
        const unsigned long long key =
            ((unsigned long long)ord << 32) | (unsigned long long)(uint32_t)code;
        atomicMin(&packed[row], key);
    }
}

// ---------------- unpack refined indices (separate kernel: packed must be
// fully consumed before vq_gather overwrites its d_out region) ----------------
__global__ __launch_bounds__(256) void vq_unpack(const int* __restrict__ flagged,
                                                 const int* __restrict__ cnt,
                                                 const unsigned long long* __restrict__ packed,
                                                 int* __restrict__ idx) {
    const int n = *cnt;
    for (int g = blockIdx.x * 256 + threadIdx.x; g < n; g += gridDim.x * 256) {
        const int row = flagged[g];
        idx[row] = (int)(packed[row] & 0xffffffffull);
    }
}

// ---------------- gather ----------------
__global__ __launch_bounds__(256) void vq_gather(const float* __restrict__ w,
                                                 const int* __restrict__ idx,
                                                 float* __restrict__ outq,
                                                 float* __restrict__ outi) {
    const int t    = threadIdx.x;
    const int lane = t & 63;
    const int sub  = t >> 6;
    const int row0 = blockIdx.x * 128;
    #pragma unroll 4
    for (int it = 0; it < 32; ++it) {
        const int row = row0 + it * 4 + sub;
        const int j   = idx[row];
        ((float4*)outq)[(size_t)row * 64 + lane] = ((const float4*)w)[(size_t)j * 64 + lane];
        if (lane == 0) outi[row] = (float)j;
    }
}

extern "C" void kernel_launch(void* const* d_in, const int* in_sizes, int n_in,
                              void* d_out, int out_size, void* d_ws, size_t ws_size,
                              hipStream_t stream) {
    const float* z = (const float*)d_in[0];
    const float* w = (const float*)d_in[1];
    float* outq = (float*)d_out;
    float* outi = outq + (size_t)NROWS * D;

    // scratch inside d_out (all dead before vq_gather):
    //   zbf   [0, 32MB)        bf16 z
    //   wbf   [32MB, 32.5MB)   bf16 w
    //   Cn    [32.5MB, +4KB)   |w|^2
    //   m1g   [35MB, +256KB)   per-row screen min1
    //   packed[35.5MB, +512KB) per-row (ordered-d, code) u64
    //   pairs [36MB, ...)      candidate (row<<16|code) u32, cap MAXPAIRS
    unsigned short*     zbf    = (unsigned short*)d_out;
    unsigned short*     wbf    = (unsigned short*)((char*)d_out + 33554432);
    float*              Cn     = (float*)((char*)d_out + 34078720);
    float*              m1g    = (float*)((char*)d_out + 36700160);
    unsigned long long* packed = (unsigned long long*)((char*)d_out + 37224448);
    uint32_t*           pairs  = (uint32_t*)((char*)d_out + 37748736);

    char* ws      = (char*)d_ws;
    int*  idx     = (int*)ws;
    int*  flagged = (int*)(ws + 262144);
    int*  cnt     = (int*)(ws + 524288);
    int*  pcnt    = (int*)(ws + 524292);

    vq_prep<<<8580, 256, 0, stream>>>(z, zbf, w, wbf, Cn, cnt, pcnt, packed);
    vq_screen<<<NROWS / 128, 256, 0, stream>>>(zbf, wbf, Cn, idx, flagged, cnt, m1g);
    vq_cand<<<512, 256, 0, stream>>>(zbf, wbf, Cn, m1g, flagged, cnt, pairs, pcnt);
    vq_exact<<<256, 256, 0, stream>>>(z, w, Cn, pairs, pcnt, packed);
    vq_unpack<<<64, 256, 0, stream>>>(flagged, cnt, packed, idx);
    vq_gather<<<NROWS / 128, 256, 0, stream>>>(w, idx, outq, outi);
}